// Round 1
// baseline (440.087 us; speedup 1.0000x reference)
//
#include <hip/hip_runtime.h>
#include <hip/hip_bf16.h>

#define B_ 32
#define N_ 512
#define D_ 512
#define E_ 8
#define P_ 96
#define KC 25
#define H_ 4
#define DK 128
#define HE 32
#define BN 16384

typedef short short8 __attribute__((ext_vector_type(8)));
typedef float f32x4 __attribute__((ext_vector_type(4)));

// ws offsets (in floats)
#define OQ    0
#define OM    4096
#define OC    20480
#define OA    20736      /* 2 x 524288 partial logits -> softmaxed A in first half */
#define OU    1069312    /* 524288 */
#define OAP   1593600    /* 131072 */
#define OATT  1724672    /* 131072 */
#define OWPT  1855744    /* 393216 */
#define OZC   2248960    /* 24576 */
#define OCNT  2273536    /* 8 ints */
#define OTOK  2273792    /* 131072 ints */
#define OWEFF 2404864    /* 786432 bf16 = 393216 float slots */

__device__ __forceinline__ float b2f(short s) {
  unsigned u = ((unsigned)(unsigned short)s) << 16;
  return __builtin_bit_cast(float, u);
}
__device__ __forceinline__ unsigned short f2b(float f) {
  return __builtin_bit_cast(unsigned short, __float2bfloat16(f));
}

// q[e][i] = router[e]·Wq[:,i] + bq[i]
__global__ __launch_bounds__(256) void k_q(const float* __restrict__ router,
        const float* __restrict__ Wq, const float* __restrict__ bq,
        float* __restrict__ q) {
  int i = blockIdx.x * 256 + threadIdx.x;
  float acc[E_];
#pragma unroll
  for (int e = 0; e < E_; ++e) acc[e] = bq[i];
  for (int d = 0; d < D_; ++d) {
    float w = Wq[d * D_ + i];
#pragma unroll
    for (int e = 0; e < E_; ++e) acc[e] = fmaf(router[e * D_ + d], w, acc[e]);
  }
#pragma unroll
  for (int e = 0; e < E_; ++e) q[e * D_ + i] = acc[e];
}

// M[he][d0] = sum_j Wk[d0, h*128+j] * q[e, h*128+j];  c[he] = q[e,h-blk]·bk[h-blk]
__global__ __launch_bounds__(256) void k_m(const float* __restrict__ Wk,
        const float* __restrict__ bk, const float* __restrict__ q,
        float* __restrict__ M, float* __restrict__ c) {
  int he = blockIdx.x >> 1;
  int ch = blockIdx.x & 1;
  int d0 = ch * 256 + threadIdx.x;
  int h = he >> 3, e = he & 7;
  const float* qrow = q + e * D_ + h * DK;
  const float* wrow = Wk + d0 * D_ + h * DK;
  float acc = 0.f;
  for (int j = 0; j < DK; j += 4) {
    float4 wv = *(const float4*)(wrow + j);
    float4 qv = *(const float4*)(qrow + j);
    acc = fmaf(wv.x, qv.x, acc); acc = fmaf(wv.y, qv.y, acc);
    acc = fmaf(wv.z, qv.z, acc); acc = fmaf(wv.w, qv.w, acc);
  }
  M[he * D_ + d0] = acc;
  if (ch == 0 && threadIdx.x == 0) {
    float cc = 0.f;
    for (int j = 0; j < DK; ++j) cc = fmaf(qrow[j], bk[h * DK + j], cc);
    c[he] = cc;
  }
}

// partial logits (raw dot over a d-half): Apart[dh][b][he][n] = x[b,n,dh-half]·M[he,dh-half]
__global__ __launch_bounds__(256) void k_logits(const float* __restrict__ x,
        const float* __restrict__ M, float* __restrict__ Apart) {
  __shared__ float xs[32 * 257];
  int dh = blockIdx.x & 1;
  int nt = (blockIdx.x >> 1) & 15;
  int b = blockIdx.x >> 5;
  const float* xb = x + (b * N_ + nt * 32) * D_ + dh * 256;
  for (int idx = threadIdx.x; idx < 32 * 256; idx += 256) {
    int r = idx >> 8, cc = idx & 255;
    xs[r * 257 + cc] = xb[r * D_ + cc];
  }
  __syncthreads();
  int n = threadIdx.x & 31, heg = threadIdx.x >> 5;
  const float* xr = xs + n * 257;
  float acc[4] = {0.f, 0.f, 0.f, 0.f};
  for (int d = 0; d < 256; d += 4) {
    float x0 = xr[d], x1 = xr[d + 1], x2 = xr[d + 2], x3 = xr[d + 3];
#pragma unroll
    for (int i = 0; i < 4; ++i) {
      float4 mv = *(const float4*)(M + (heg + 8 * i) * D_ + dh * 256 + d);
      acc[i] = fmaf(x0, mv.x, acc[i]);
      acc[i] = fmaf(x1, mv.y, acc[i]);
      acc[i] = fmaf(x2, mv.z, acc[i]);
      acc[i] = fmaf(x3, mv.w, acc[i]);
    }
  }
  int ncol = nt * 32 + n;
  float* Ad = Apart + dh * (B_ * HE * N_);
#pragma unroll
  for (int i = 0; i < 4; ++i)
    Ad[(b * HE + heg + 8 * i) * N_ + ncol] = acc[i];
}

// softmax over n per (b,he) row; combines d-half partials, applies scale and c[he]
__global__ __launch_bounds__(256) void k_softmax(float* __restrict__ A0,
        const float* __restrict__ A1, const float* __restrict__ c) {
  int row = blockIdx.x;
  float* p0 = A0 + row * N_;
  const float* p1 = A1 + row * N_;
  float cc = c[row & 31];
  int t = threadIdx.x;
  const float scale = 0.08838834764831845f;
  float v0 = scale * (p0[t] + p1[t] + cc);
  float v1 = scale * (p0[t + 256] + p1[t + 256] + cc);
  __shared__ float red[4], red2[4];
  float m = fmaxf(v0, v1);
#pragma unroll
  for (int off = 32; off; off >>= 1) m = fmaxf(m, __shfl_xor(m, off));
  if ((t & 63) == 0) red[t >> 6] = m;
  __syncthreads();
  m = fmaxf(fmaxf(red[0], red[1]), fmaxf(red[2], red[3]));
  float e0 = expf(v0 - m), e1 = expf(v1 - m);
  float s = e0 + e1;
#pragma unroll
  for (int off = 32; off; off >>= 1) s += __shfl_xor(s, off);
  if ((t & 63) == 0) red2[t >> 6] = s;
  __syncthreads();
  s = red2[0] + red2[1] + red2[2] + red2[3];
  float inv = 1.0f / s;
  p0[t] = e0 * inv;
  p0[t + 256] = e1 * inv;
}

// u[b][he][d] = sum_n A[b,he,n] * x[b,n,d]
__global__ __launch_bounds__(256) void k_u(const float* __restrict__ x,
        const float* __restrict__ A, float* __restrict__ u) {
  __shared__ float As[8 * N_];
  int b = blockIdx.x >> 2, g = blockIdx.x & 3;
  const float* Ab = A + (b * HE + g * 8) * N_;
  for (int idx = threadIdx.x; idx < 8 * N_; idx += 256) As[idx] = Ab[idx];
  __syncthreads();
  int dq = (threadIdx.x & 127) * 4;
  int hq = threadIdx.x >> 7;
  const float* As0 = As + hq * 4 * N_;
  const float* xb = x + b * N_ * D_ + dq;
  float acc[4][4] = {{0.f}};
  for (int n = 0; n < N_; n += 4) {
    float a[4][4], xf[4][4];
#pragma unroll
    for (int i = 0; i < 4; ++i) {
      float4 t = *(const float4*)(As0 + i * N_ + n);
      a[i][0] = t.x; a[i][1] = t.y; a[i][2] = t.z; a[i][3] = t.w;
    }
#pragma unroll
    for (int k = 0; k < 4; ++k) {
      float4 t = *(const float4*)(xb + (n + k) * D_);
      xf[k][0] = t.x; xf[k][1] = t.y; xf[k][2] = t.z; xf[k][3] = t.w;
    }
#pragma unroll
    for (int i = 0; i < 4; ++i)
#pragma unroll
      for (int j = 0; j < 4; ++j) {
        float s = acc[i][j];
        s = fmaf(a[i][0], xf[0][j], s);
        s = fmaf(a[i][1], xf[1][j], s);
        s = fmaf(a[i][2], xf[2][j], s);
        s = fmaf(a[i][3], xf[3][j], s);
        acc[i][j] = s;
      }
  }
#pragma unroll
  for (int i = 0; i < 4; ++i) {
    float4 o; o.x = acc[i][0]; o.y = acc[i][1]; o.z = acc[i][2]; o.w = acc[i][3];
    *(float4*)(u + (b * HE + g * 8 + hq * 4 + i) * D_ + dq) = o;
  }
}

// att_pre[b][e][i] = sum_d u[b, h(i)*8+e, d] * Wv[d,i] + bv[i]   (h(i)=i>>7)
__global__ __launch_bounds__(256) void k_attpre(const float* __restrict__ u,
        const float* __restrict__ Wv, const float* __restrict__ bv,
        float* __restrict__ ap) {
  __shared__ float us[8 * D_];
  int e = blockIdx.x & 7;
  int ic = (blockIdx.x >> 3) & 3;
  int bq = blockIdx.x >> 5;
  for (int idx = threadIdx.x; idx < 8 * D_; idx += 256) {
    int rr = idx >> 9, d = idx & 511;
    us[idx] = u[((bq * 8 + rr) * HE + ic * 8 + e) * D_ + d];
  }
  __syncthreads();
  int i = ic * 128 + (threadIdx.x & 127);
  int bg = threadIdx.x >> 7;
  const float* usb = us + bg * 4 * D_;
  float acc[4] = {0.f, 0.f, 0.f, 0.f};
  for (int d = 0; d < D_; d += 4) {
    float w0 = Wv[(d + 0) * D_ + i];
    float w1 = Wv[(d + 1) * D_ + i];
    float w2 = Wv[(d + 2) * D_ + i];
    float w3 = Wv[(d + 3) * D_ + i];
#pragma unroll
    for (int r = 0; r < 4; ++r) {
      float4 uv = *(const float4*)(usb + r * D_ + d);
      float s = acc[r];
      s = fmaf(uv.x, w0, s); s = fmaf(uv.y, w1, s);
      s = fmaf(uv.z, w2, s); s = fmaf(uv.w, w3, s);
      acc[r] = s;
    }
  }
  float bvi = bv[i];
#pragma unroll
  for (int r = 0; r < 4; ++r)
    ap[((bq * 8 + bg * 4 + r) * E_ + e) * D_ + i] = acc[r] + bvi;
}

// att[b][e][o] = sum_i ap[b,e,i] * Wo[i,o] + bo[o]
__global__ __launch_bounds__(256) void k_att(const float* __restrict__ ap,
        const float* __restrict__ Wo, const float* __restrict__ bo,
        float* __restrict__ att) {
  __shared__ float ps[8 * D_];
  int b = blockIdx.x >> 2, oc = blockIdx.x & 3;
  for (int idx = threadIdx.x; idx < 8 * D_; idx += 256)
    ps[idx] = ap[b * E_ * D_ + idx];
  __syncthreads();
  int o = oc * 128 + (threadIdx.x & 127);
  int eg = threadIdx.x >> 7;
  const float* pe = ps + eg * 4 * D_;
  float acc[4] = {0.f, 0.f, 0.f, 0.f};
  for (int i2 = 0; i2 < D_; i2 += 4) {
    float w0 = Wo[(i2 + 0) * D_ + o];
    float w1 = Wo[(i2 + 1) * D_ + o];
    float w2 = Wo[(i2 + 2) * D_ + o];
    float w3 = Wo[(i2 + 3) * D_ + o];
#pragma unroll
    for (int r = 0; r < 4; ++r) {
      float4 pv = *(const float4*)(pe + r * D_ + i2);
      float s = acc[r];
      s = fmaf(pv.x, w0, s); s = fmaf(pv.y, w1, s);
      s = fmaf(pv.z, w2, s); s = fmaf(pv.w, w3, s);
      acc[r] = s;
    }
  }
  float boo = bo[o];
#pragma unroll
  for (int r = 0; r < 4; ++r)
    att[(b * E_ + eg * 4 + r) * D_ + o] = acc[r] + boo;
}

// WpT[e][p][l] = Wp[e][l][p]
__global__ __launch_bounds__(256) void k_wpt(const float* __restrict__ Wp,
        float* __restrict__ WpT) {
  __shared__ float tile[64 * 97];
  int e = blockIdx.x >> 3, lt = blockIdx.x & 7;
  for (int idx = threadIdx.x; idx < 64 * 96; idx += 256) {
    int l = idx / 96, p = idx - l * 96;
    tile[l * 97 + p] = Wp[(e * D_ + lt * 64 + l) * P_ + p];
  }
  __syncthreads();
  for (int idx = threadIdx.x; idx < 96 * 64; idx += 256) {
    int p = idx >> 6, l = idx & 63;
    WpT[(e * P_ + p) * D_ + lt * 64 + l] = tile[l * 97 + p];
  }
}

// weff (bf16) [e][j][p][m] = sum_k Wc[e,j,k] * Wp[e, m-k+12, p]
__global__ __launch_bounds__(256) void k_weff(const float* __restrict__ Wc,
        const float* __restrict__ WpT, __hip_bfloat16* __restrict__ weff) {
  int flat = blockIdx.x * 256 + threadIdx.x;
  int m = flat & 511;
  int rest = flat >> 9;       // (e*2+j)*96 + p
  int p = rest % 96;
  int ej = rest / 96;
  int e = ej >> 1, j = ej & 1;
  const float* wprow = WpT + (e * P_ + p) * D_;
  const float* wc = Wc + (e * 2 + j) * KC;
  float acc = 0.f;
#pragma unroll
  for (int k = 0; k < KC; ++k) {
    int l = m - k + 12;
    if (l >= 0 && l < D_) acc = fmaf(wc[k], wprow[l], acc);
  }
  weff[flat] = __float2bfloat16(acc);
}

// routing: argmax_e (att[b,e]·x[b,n]) / ||att[b,e]|| ; append token to expert list
__global__ __launch_bounds__(256) void k_route(const float* __restrict__ x,
        const float* __restrict__ att, int* __restrict__ cnt,
        int* __restrict__ tok) {
  __shared__ float xs[16 * 516];
  __shared__ float as_[8 * D_];
  __shared__ float rn[8];
  __shared__ float sc2[256];
  __shared__ float sc[128];
  int b = blockIdx.x >> 5, nt = blockIdx.x & 31;
  const float* xb = x + (b * N_ + nt * 16) * D_;
  for (int idx = threadIdx.x; idx < 16 * 128; idx += 256) {
    int r = idx >> 7, c4 = (idx & 127) * 4;
    *(float4*)(xs + r * 516 + c4) = *(const float4*)(xb + r * D_ + c4);
  }
  for (int idx = threadIdx.x; idx < 8 * D_; idx += 256)
    as_[idx] = att[b * E_ * D_ + idx];
  __syncthreads();
  {
    int e = threadIdx.x >> 5, l = threadIdx.x & 31;
    float s = 0.f;
    for (int d = l; d < D_; d += 32) { float v = as_[e * D_ + d]; s = fmaf(v, v, s); }
#pragma unroll
    for (int off = 16; off; off >>= 1) s += __shfl_xor(s, off);
    if (l == 0) rn[e] = 1.0f / sqrtf(s);
  }
  int n = threadIdx.x & 15, e8 = (threadIdx.x >> 4) & 7, h2 = threadIdx.x >> 7;
  const float* xr = xs + n * 516 + h2 * 256;
  const float* ar = as_ + e8 * D_ + h2 * 256;
  float acc = 0.f;
  for (int d = 0; d < 256; d += 4) {
    float4 xv = *(const float4*)(xr + d);
    float4 av = *(const float4*)(ar + d);
    acc = fmaf(xv.x, av.x, acc); acc = fmaf(xv.y, av.y, acc);
    acc = fmaf(xv.z, av.z, acc); acc = fmaf(xv.w, av.w, acc);
  }
  sc2[threadIdx.x] = acc;
  __syncthreads();
  if (threadIdx.x < 128) {
    int e = threadIdx.x >> 4;
    sc[threadIdx.x] = (sc2[threadIdx.x] + sc2[threadIdx.x + 128]) * rn[e];
  }
  __syncthreads();
  if (threadIdx.x < 16) {
    int nn = threadIdx.x;
    float best = sc[nn]; int bi = 0;
#pragma unroll
    for (int ee = 1; ee < 8; ++ee) {
      float v = sc[ee * 16 + nn];
      if (v > best) { best = v; bi = ee; }
    }
    int tg = b * N_ + nt * 16 + nn;
    int slot = atomicAdd(&cnt[bi], 1);
    tok[bi * BN + slot] = tg;
  }
}

// zc[b][e][p] = att[b,e]·weff[e,1,:,p] + bc[e]*sum_l Wp[e,l,p] + bp[e,p]
__global__ __launch_bounds__(128) void k_zc(const float* __restrict__ att,
        const __hip_bfloat16* __restrict__ weff, const float* __restrict__ WpT,
        const float* __restrict__ bc, const float* __restrict__ bp,
        float* __restrict__ zc) {
  int b = blockIdx.x >> 3, e = blockIdx.x & 7;
  int p = threadIdx.x;
  if (p >= P_) return;
  const short* wrow = (const short*)(weff + ((e * 2 + 1) * P_ + p) * D_);
  const float* arow = att + (b * E_ + e) * D_;
  const float* wprow = WpT + (e * P_ + p) * D_;
  float acc = 0.f, s2 = 0.f;
  for (int m = 0; m < D_; m += 8) {
    short8 w8 = *(const short8*)(wrow + m);
    float4 a0 = *(const float4*)(arow + m);
    float4 a1 = *(const float4*)(arow + m + 4);
    float4 q0 = *(const float4*)(wprow + m);
    float4 q1 = *(const float4*)(wprow + m + 4);
    acc = fmaf(a0.x, b2f(w8[0]), acc); acc = fmaf(a0.y, b2f(w8[1]), acc);
    acc = fmaf(a0.z, b2f(w8[2]), acc); acc = fmaf(a0.w, b2f(w8[3]), acc);
    acc = fmaf(a1.x, b2f(w8[4]), acc); acc = fmaf(a1.y, b2f(w8[5]), acc);
    acc = fmaf(a1.z, b2f(w8[6]), acc); acc = fmaf(a1.w, b2f(w8[7]), acc);
    s2 += q0.x + q0.y + q0.z + q0.w + q1.x + q1.y + q1.z + q1.w;
  }
  zc[(b * E_ + e) * P_ + p] = acc + bc[e] * s2 + bp[e * P_ + p];
}

// grouped final GEMM: out[t,p] = x[t]·weff[e,0,:,p] + zc[b(t),e,p]  via bf16 MFMA
__global__ __launch_bounds__(64) void k_final(const float* __restrict__ x,
        const __hip_bfloat16* __restrict__ weff, const float* __restrict__ zc,
        const int* __restrict__ cnt, const int* __restrict__ tok,
        float* __restrict__ out) {
  __shared__ __align__(16) unsigned short xsb[32 * 520];
  __shared__ int toks[32];
  int e = blockIdx.y, g = blockIdx.x;
  int cnt_e = cnt[e];
  int base = g * 32;
  if (base >= cnt_e) return;
  int cl = cnt_e - base; if (cl > 32) cl = 32;
  int lane = threadIdx.x;
  if (lane < 32) toks[lane] = (lane < cl) ? tok[e * BN + base + lane] : 0;
  __syncthreads();
  for (int idx = lane; idx < 32 * 128; idx += 64) {
    int r = idx >> 7, c4 = (idx & 127) * 4;
    float4 v = {0.f, 0.f, 0.f, 0.f};
    if (r < cl) v = *(const float4*)(x + toks[r] * D_ + c4);
    ushort4 u4;
    u4.x = f2b(v.x); u4.y = f2b(v.y); u4.z = f2b(v.z); u4.w = f2b(v.w);
    *(ushort4*)(xsb + r * 520 + c4) = u4;
  }
  __syncthreads();
  int m16 = lane & 15, quad = lane >> 4;
  const short* w0 = (const short*)(weff + (e * 2 + 0) * P_ * D_);
  f32x4 acc[2][6];
#pragma unroll
  for (int a = 0; a < 2; ++a)
#pragma unroll
    for (int cc = 0; cc < 6; ++cc) acc[a][cc] = (f32x4){0.f, 0.f, 0.f, 0.f};
  for (int kt = 0; kt < 16; ++kt) {
    int koff = kt * 32 + quad * 8;
    short8 a0 = *(const short8*)((const short*)xsb + (m16) * 520 + koff);
    short8 a1 = *(const short8*)((const short*)xsb + (16 + m16) * 520 + koff);
#pragma unroll
    for (int nt = 0; nt < 6; ++nt) {
      short8 bf = *(const short8*)(w0 + (nt * 16 + m16) * D_ + koff);
      acc[0][nt] = __builtin_amdgcn_mfma_f32_16x16x32_bf16(a0, bf, acc[0][nt], 0, 0, 0);
      acc[1][nt] = __builtin_amdgcn_mfma_f32_16x16x32_bf16(a1, bf, acc[1][nt], 0, 0, 0);
    }
  }
#pragma unroll
  for (int mt = 0; mt < 2; ++mt)
#pragma unroll
    for (int nt = 0; nt < 6; ++nt)
#pragma unroll
      for (int rr = 0; rr < 4; ++rr) {
        int row = mt * 16 + quad * 4 + rr;
        if (row < cl) {
          int tg = toks[row];
          int bb = tg >> 9;
          int p = nt * 16 + m16;
          out[tg * P_ + p] = acc[mt][nt][rr] + zc[(bb * E_ + e) * P_ + p];
        }
      }
}

extern "C" void kernel_launch(void* const* d_in, const int* in_sizes, int n_in,
                              void* d_out, int out_size, void* d_ws, size_t ws_size,
                              hipStream_t stream) {
  const float* x      = (const float*)d_in[0];
  const float* router = (const float*)d_in[1];
  const float* Wq     = (const float*)d_in[2];
  const float* bq     = (const float*)d_in[3];
  const float* Wk     = (const float*)d_in[4];
  const float* bk     = (const float*)d_in[5];
  const float* Wv     = (const float*)d_in[6];
  const float* bv     = (const float*)d_in[7];
  const float* Wo     = (const float*)d_in[8];
  const float* bo     = (const float*)d_in[9];
  const float* Wc     = (const float*)d_in[10];
  const float* bc     = (const float*)d_in[11];
  const float* Wp     = (const float*)d_in[12];
  const float* bp     = (const float*)d_in[13];
  float* out = (float*)d_out;
  float* w = (float*)d_ws;

  float* q    = w + OQ;
  float* M    = w + OM;
  float* c    = w + OC;
  float* A0   = w + OA;
  float* A1   = w + OA + B_ * HE * N_;
  float* u    = w + OU;
  float* ap   = w + OAP;
  float* att  = w + OATT;
  float* WpT  = w + OWPT;
  float* zc   = w + OZC;
  int*   cnt  = (int*)(w + OCNT);
  int*   tok  = (int*)(w + OTOK);
  __hip_bfloat16* weff = (__hip_bfloat16*)(w + OWEFF);

  hipMemsetAsync(cnt, 0, E_ * sizeof(int), stream);
  k_q<<<2, 256, 0, stream>>>(router, Wq, bq, q);
  k_m<<<64, 256, 0, stream>>>(Wk, bk, q, M, c);
  k_logits<<<1024, 256, 0, stream>>>(x, M, A0);
  k_softmax<<<1024, 256, 0, stream>>>(A0, A1, c);
  k_u<<<128, 256, 0, stream>>>(x, A0, u);
  k_attpre<<<128, 256, 0, stream>>>(u, Wv, bv, ap);
  k_att<<<128, 256, 0, stream>>>(ap, Wo, bo, att);
  k_wpt<<<64, 256, 0, stream>>>(Wp, WpT);
  k_weff<<<3072, 256, 0, stream>>>(Wc, WpT, weff);
  k_route<<<1024, 256, 0, stream>>>(x, att, cnt, tok);
  k_zc<<<256, 128, 0, stream>>>(att, weff, WpT, bc, bp, zc);
  k_final<<<dim3(512, 8), 64, 0, stream>>>(x, weff, zc, cnt, tok, out);
}

// Round 2
// 336.592 us; speedup vs baseline: 1.3075x; 1.3075x over previous
//
#include <hip/hip_runtime.h>
#include <hip/hip_bf16.h>

#define B_ 32
#define N_ 512
#define D_ 512
#define E_ 8
#define P_ 96
#define KC 25
#define H_ 4
#define DK 128
#define HE 32
#define BN 16384

typedef short short8 __attribute__((ext_vector_type(8)));
typedef float f32x4 __attribute__((ext_vector_type(4)));

// ws offsets (in floats)
#define OQ    0
#define OM    4096
#define OC    20480
#define OA    20736      /* 2 x 524288 partial logits -> softmaxed A in first half */
#define OU    1069312    /* 524288 */
#define OAP   1593600    /* 131072 */
#define OATT  1724672    /* 131072 */
#define OWPT  1855744    /* 393216 */
#define OZC   2248960    /* 24576 */
#define OCNT  2273536    /* 256 ints (8 counters strided by 32) */
#define OTOK  2273792    /* 131072 ints */
#define OWEFF 2404864    /* 786432 bf16 = 393216 float slots */
#define OUP   2798080    /* 4194304 floats: u partials [b][nq][32][512] */

__device__ __forceinline__ float b2f(short s) {
  unsigned u = ((unsigned)(unsigned short)s) << 16;
  return __builtin_bit_cast(float, u);
}
__device__ __forceinline__ unsigned short f2b(float f) {
  return __builtin_bit_cast(unsigned short, __float2bfloat16(f));
}

// q[e][i] = router[e]·Wq[:,i] + bq[i]
__global__ __launch_bounds__(256) void k_q(const float* __restrict__ router,
        const float* __restrict__ Wq, const float* __restrict__ bq,
        float* __restrict__ q) {
  int i = blockIdx.x * 256 + threadIdx.x;
  float acc[E_];
#pragma unroll
  for (int e = 0; e < E_; ++e) acc[e] = bq[i];
  for (int d = 0; d < D_; ++d) {
    float w = Wq[d * D_ + i];
#pragma unroll
    for (int e = 0; e < E_; ++e) acc[e] = fmaf(router[e * D_ + d], w, acc[e]);
  }
#pragma unroll
  for (int e = 0; e < E_; ++e) q[e * D_ + i] = acc[e];
}

// M[he][d0] = sum_j Wk[d0, h*128+j] * q[e, h*128+j];  c[he] = q[e,h-blk]·bk[h-blk]
__global__ __launch_bounds__(256) void k_m(const float* __restrict__ Wk,
        const float* __restrict__ bk, const float* __restrict__ q,
        float* __restrict__ M, float* __restrict__ c) {
  int he = blockIdx.x >> 1;
  int ch = blockIdx.x & 1;
  int d0 = ch * 256 + threadIdx.x;
  int h = he >> 3, e = he & 7;
  const float* qrow = q + e * D_ + h * DK;
  const float* wrow = Wk + d0 * D_ + h * DK;
  float acc = 0.f;
  for (int j = 0; j < DK; j += 4) {
    float4 wv = *(const float4*)(wrow + j);
    float4 qv = *(const float4*)(qrow + j);
    acc = fmaf(wv.x, qv.x, acc); acc = fmaf(wv.y, qv.y, acc);
    acc = fmaf(wv.z, qv.z, acc); acc = fmaf(wv.w, qv.w, acc);
  }
  M[he * D_ + d0] = acc;
  if (ch == 0 && threadIdx.x == 0) {
    float cc = 0.f;
    for (int j = 0; j < DK; ++j) cc = fmaf(qrow[j], bk[h * DK + j], cc);
    c[he] = cc;
  }
}

// partial logits (raw dot over a d-half): Apart[dh][b][he][n] = x[b,n,dh-half]·M[he,dh-half]
__global__ __launch_bounds__(256) void k_logits(const float* __restrict__ x,
        const float* __restrict__ M, float* __restrict__ Apart) {
  __shared__ float xs[32 * 257];
  int dh = blockIdx.x & 1;
  int nt = (blockIdx.x >> 1) & 15;
  int b = blockIdx.x >> 5;
  const float* xb = x + (b * N_ + nt * 32) * D_ + dh * 256;
  for (int idx = threadIdx.x; idx < 32 * 256; idx += 256) {
    int r = idx >> 8, cc = idx & 255;
    xs[r * 257 + cc] = xb[r * D_ + cc];
  }
  __syncthreads();
  int n = threadIdx.x & 31, heg = threadIdx.x >> 5;
  const float* xr = xs + n * 257;
  float acc[4] = {0.f, 0.f, 0.f, 0.f};
  for (int d = 0; d < 256; d += 4) {
    float x0 = xr[d], x1 = xr[d + 1], x2 = xr[d + 2], x3 = xr[d + 3];
#pragma unroll
    for (int i = 0; i < 4; ++i) {
      float4 mv = *(const float4*)(M + (heg + 8 * i) * D_ + dh * 256 + d);
      acc[i] = fmaf(x0, mv.x, acc[i]);
      acc[i] = fmaf(x1, mv.y, acc[i]);
      acc[i] = fmaf(x2, mv.z, acc[i]);
      acc[i] = fmaf(x3, mv.w, acc[i]);
    }
  }
  int ncol = nt * 32 + n;
  float* Ad = Apart + dh * (B_ * HE * N_);
#pragma unroll
  for (int i = 0; i < 4; ++i)
    Ad[(b * HE + heg + 8 * i) * N_ + ncol] = acc[i];
}

// softmax over n per (b,he) row; combines d-half partials, applies scale and c[he]
__global__ __launch_bounds__(256) void k_softmax(float* __restrict__ A0,
        const float* __restrict__ A1, const float* __restrict__ c) {
  int row = blockIdx.x;
  float* p0 = A0 + row * N_;
  const float* p1 = A1 + row * N_;
  float cc = c[row & 31];
  int t = threadIdx.x;
  const float scale = 0.08838834764831845f;
  float v0 = scale * (p0[t] + p1[t] + cc);
  float v1 = scale * (p0[t + 256] + p1[t + 256] + cc);
  __shared__ float red[4], red2[4];
  float m = fmaxf(v0, v1);
#pragma unroll
  for (int off = 32; off; off >>= 1) m = fmaxf(m, __shfl_xor(m, off));
  if ((t & 63) == 0) red[t >> 6] = m;
  __syncthreads();
  m = fmaxf(fmaxf(red[0], red[1]), fmaxf(red[2], red[3]));
  float e0 = expf(v0 - m), e1 = expf(v1 - m);
  float s = e0 + e1;
#pragma unroll
  for (int off = 32; off; off >>= 1) s += __shfl_xor(s, off);
  if ((t & 63) == 0) red2[t >> 6] = s;
  __syncthreads();
  s = red2[0] + red2[1] + red2[2] + red2[3];
  float inv = 1.0f / s;
  p0[t] = e0 * inv;
  p0[t + 256] = e1 * inv;
}

// u partials over n-slices: up[b][nq][he][d] = sum_{n in slice} A[b,he,n]*x[b,n,d]
// grid (nq=8, b=32), 512 threads; A staged transposed in LDS (broadcast reads);
// x read exactly once across the whole grid.
__global__ __launch_bounds__(512) void k_u2(const float* __restrict__ x,
        const float* __restrict__ A, float* __restrict__ up) {
  __shared__ float As[64 * 33];
  int nq = blockIdx.x, b = blockIdx.y;
  for (int idx = threadIdx.x; idx < 64 * 32; idx += 512) {
    int n = idx & 63, he = idx >> 6;
    As[n * 33 + he] = A[(b * HE + he) * N_ + nq * 64 + n];
  }
  __syncthreads();
  int dq = threadIdx.x & 127, hg = threadIdx.x >> 7;  // hg uniform per wave
  const float* xb = x + (b * N_ + nq * 64) * D_ + dq * 4;
  float acc[8][4];
#pragma unroll
  for (int j = 0; j < 8; ++j)
#pragma unroll
    for (int k = 0; k < 4; ++k) acc[j][k] = 0.f;
  for (int n = 0; n < 64; ++n) {
    float4 xv = *(const float4*)(xb + n * D_);
    const float* ar = As + n * 33 + hg * 8;
#pragma unroll
    for (int j = 0; j < 8; ++j) {
      float a = ar[j];
      acc[j][0] = fmaf(a, xv.x, acc[j][0]);
      acc[j][1] = fmaf(a, xv.y, acc[j][1]);
      acc[j][2] = fmaf(a, xv.z, acc[j][2]);
      acc[j][3] = fmaf(a, xv.w, acc[j][3]);
    }
  }
  float* o = up + (((b * 8 + nq) * HE) + hg * 8) * D_ + dq * 4;
#pragma unroll
  for (int j = 0; j < 8; ++j) {
    float4 v; v.x = acc[j][0]; v.y = acc[j][1]; v.z = acc[j][2]; v.w = acc[j][3];
    *(float4*)(o + j * D_) = v;
  }
}

// u[b][he][d] = sum_nq up[b][nq][he][d]
__global__ __launch_bounds__(256) void k_ured(const float* __restrict__ up,
        float* __restrict__ u) {
  int o4 = (blockIdx.x * 256 + threadIdx.x) * 4;
  int bhe = o4 >> 9, d = o4 & 511;
  int b = bhe >> 5, he = bhe & 31;
  float4 s = {0.f, 0.f, 0.f, 0.f};
#pragma unroll
  for (int nq = 0; nq < 8; ++nq) {
    float4 v = *(const float4*)(up + (((b * 8 + nq) * HE + he) << 9) + d);
    s.x += v.x; s.y += v.y; s.z += v.z; s.w += v.w;
  }
  *(float4*)(u + o4) = s;
}

// att_pre[b][e][i] = sum_d u[b, h(i)*8+e, d] * Wv[d,i] + bv[i]   (h(i)=i>>7)
__global__ __launch_bounds__(256) void k_attpre(const float* __restrict__ u,
        const float* __restrict__ Wv, const float* __restrict__ bv,
        float* __restrict__ ap) {
  __shared__ float us[8 * D_];
  int e = blockIdx.x & 7;
  int ic = (blockIdx.x >> 3) & 3;
  int bq = blockIdx.x >> 5;
  for (int idx = threadIdx.x; idx < 8 * D_; idx += 256) {
    int rr = idx >> 9, d = idx & 511;
    us[idx] = u[((bq * 8 + rr) * HE + ic * 8 + e) * D_ + d];
  }
  __syncthreads();
  int i = ic * 128 + (threadIdx.x & 127);
  int bg = threadIdx.x >> 7;
  const float* usb = us + bg * 4 * D_;
  float acc[4] = {0.f, 0.f, 0.f, 0.f};
  for (int d = 0; d < D_; d += 4) {
    float w0 = Wv[(d + 0) * D_ + i];
    float w1 = Wv[(d + 1) * D_ + i];
    float w2 = Wv[(d + 2) * D_ + i];
    float w3 = Wv[(d + 3) * D_ + i];
#pragma unroll
    for (int r = 0; r < 4; ++r) {
      float4 uv = *(const float4*)(usb + r * D_ + d);
      float s = acc[r];
      s = fmaf(uv.x, w0, s); s = fmaf(uv.y, w1, s);
      s = fmaf(uv.z, w2, s); s = fmaf(uv.w, w3, s);
      acc[r] = s;
    }
  }
  float bvi = bv[i];
#pragma unroll
  for (int r = 0; r < 4; ++r)
    ap[((bq * 8 + bg * 4 + r) * E_ + e) * D_ + i] = acc[r] + bvi;
}

// att[b][e][o] = sum_i ap[b,e,i] * Wo[i,o] + bo[o]
__global__ __launch_bounds__(256) void k_att(const float* __restrict__ ap,
        const float* __restrict__ Wo, const float* __restrict__ bo,
        float* __restrict__ att) {
  __shared__ float ps[8 * D_];
  int b = blockIdx.x >> 2, oc = blockIdx.x & 3;
  for (int idx = threadIdx.x; idx < 8 * D_; idx += 256)
    ps[idx] = ap[b * E_ * D_ + idx];
  __syncthreads();
  int o = oc * 128 + (threadIdx.x & 127);
  int eg = threadIdx.x >> 7;
  const float* pe = ps + eg * 4 * D_;
  float acc[4] = {0.f, 0.f, 0.f, 0.f};
  for (int i2 = 0; i2 < D_; i2 += 4) {
    float w0 = Wo[(i2 + 0) * D_ + o];
    float w1 = Wo[(i2 + 1) * D_ + o];
    float w2 = Wo[(i2 + 2) * D_ + o];
    float w3 = Wo[(i2 + 3) * D_ + o];
#pragma unroll
    for (int r = 0; r < 4; ++r) {
      float4 pv = *(const float4*)(pe + r * D_ + i2);
      float s = acc[r];
      s = fmaf(pv.x, w0, s); s = fmaf(pv.y, w1, s);
      s = fmaf(pv.z, w2, s); s = fmaf(pv.w, w3, s);
      acc[r] = s;
    }
  }
  float boo = bo[o];
#pragma unroll
  for (int r = 0; r < 4; ++r)
    att[(b * E_ + eg * 4 + r) * D_ + o] = acc[r] + boo;
}

// WpT[e][p][l] = Wp[e][l][p]
__global__ __launch_bounds__(256) void k_wpt(const float* __restrict__ Wp,
        float* __restrict__ WpT) {
  __shared__ float tile[64 * 97];
  int e = blockIdx.x >> 3, lt = blockIdx.x & 7;
  for (int idx = threadIdx.x; idx < 64 * 96; idx += 256) {
    int l = idx / 96, p = idx - l * 96;
    tile[l * 97 + p] = Wp[(e * D_ + lt * 64 + l) * P_ + p];
  }
  __syncthreads();
  for (int idx = threadIdx.x; idx < 96 * 64; idx += 256) {
    int p = idx >> 6, l = idx & 63;
    WpT[(e * P_ + p) * D_ + lt * 64 + l] = tile[l * 97 + p];
  }
}

// weff (bf16) [e][j][p][m] = sum_k Wc[e,j,k] * Wp[e, m-k+12, p]
__global__ __launch_bounds__(256) void k_weff(const float* __restrict__ Wc,
        const float* __restrict__ WpT, __hip_bfloat16* __restrict__ weff) {
  int flat = blockIdx.x * 256 + threadIdx.x;
  int m = flat & 511;
  int rest = flat >> 9;       // (e*2+j)*96 + p
  int p = rest % 96;
  int ej = rest / 96;
  int e = ej >> 1, j = ej & 1;
  const float* wprow = WpT + (e * P_ + p) * D_;
  const float* wc = Wc + (e * 2 + j) * KC;
  float acc = 0.f;
#pragma unroll
  for (int k = 0; k < KC; ++k) {
    int l = m - k + 12;
    if (l >= 0 && l < D_) acc = fmaf(wc[k], wprow[l], acc);
  }
  weff[flat] = __float2bfloat16(acc);
}

// routing v2: one wave per token. score[e] = att[b,e]·x[b,n] / ||att[b,e]||,
// argmax -> per-block expert lists -> one global atomic per (block,expert).
__global__ __launch_bounds__(256) void k_route2(const float* __restrict__ x,
        const float* __restrict__ att, int* __restrict__ cnt,
        int* __restrict__ tok) {
  __shared__ float att_s[8 * D_];
  __shared__ float rn[8];
  __shared__ float red[4][520];
  __shared__ int blist[8][32];
  __shared__ int bcnt[8];
  int b = blockIdx.x >> 4, tile = blockIdx.x & 15;
  for (int idx = threadIdx.x; idx < 1024; idx += 256)
    *(float4*)(att_s + idx * 4) = *(const float4*)(att + b * E_ * D_ + idx * 4);
  if (threadIdx.x < 8) bcnt[threadIdx.x] = 0;
  __syncthreads();
  {
    int e = threadIdx.x >> 5, l = threadIdx.x & 31;
    float s = 0.f;
    for (int d0 = l; d0 < D_; d0 += 32) {
      float v = att_s[e * D_ + d0];
      s = fmaf(v, v, s);
    }
#pragma unroll
    for (int off = 16; off; off >>= 1) s += __shfl_xor(s, off);
    if (l == 0) rn[e] = 1.0f / sqrtf(s);
  }
  __syncthreads();
  int w = threadIdx.x >> 6, lane = threadIdx.x & 63;
  int e2 = lane & 7, ch = lane >> 3;
  float* rw = red[w];
  for (int i = 0; i < 8; ++i) {
    int t = b * N_ + tile * 32 + w * 8 + i;
    const float* xp = x + t * D_ + lane * 8;
    float4 xa = *(const float4*)xp;
    float4 xb4 = *(const float4*)(xp + 4);
    float p[8];
#pragma unroll
    for (int e = 0; e < 8; ++e) {
      const float* apt = att_s + e * D_ + lane * 8;
      float4 a0 = *(const float4*)apt;
      float4 a1 = *(const float4*)(apt + 4);
      float s = a0.x * xa.x;
      s = fmaf(a0.y, xa.y, s); s = fmaf(a0.z, xa.z, s); s = fmaf(a0.w, xa.w, s);
      s = fmaf(a1.x, xb4.x, s); s = fmaf(a1.y, xb4.y, s);
      s = fmaf(a1.z, xb4.z, s); s = fmaf(a1.w, xb4.w, s);
      p[e] = s;
    }
#pragma unroll
    for (int e = 0; e < 8; ++e) rw[e * 65 + lane] = p[e];
    float s = 0.f;
#pragma unroll
    for (int k = 0; k < 8; ++k) s += rw[e2 * 65 + ch * 8 + k];
    s += __shfl_xor(s, 8); s += __shfl_xor(s, 16); s += __shfl_xor(s, 32);
    float sc = s * rn[e2];
    int be = e2;
#pragma unroll
    for (int off = 1; off < 8; off <<= 1) {
      float o = __shfl_xor(sc, off);
      int oe = __shfl_xor(be, off);
      if (o > sc || (o == sc && oe < be)) { sc = o; be = oe; }
    }
    if (lane == 0) {
      int slot = atomicAdd(&bcnt[be], 1);
      blist[be][slot] = t;
    }
  }
  __syncthreads();
  int e = threadIdx.x >> 5, r = threadIdx.x & 31;
  int ce = bcnt[e];
  int gs = 0;
  if (r == 0 && ce > 0) gs = atomicAdd(&cnt[e * 32], ce);
  gs = __shfl(gs, (threadIdx.x & 63) & 32);
  for (int k2 = r; k2 < ce; k2 += 32) tok[e * BN + gs + k2] = blist[e][k2];
}

// zc[b][e][p] = att[b,e]·weff[e,1,:,p] + bc[e]*sum_l Wp[e,l,p] + bp[e,p]
__global__ __launch_bounds__(128) void k_zc(const float* __restrict__ att,
        const __hip_bfloat16* __restrict__ weff, const float* __restrict__ WpT,
        const float* __restrict__ bc, const float* __restrict__ bp,
        float* __restrict__ zc) {
  int b = blockIdx.x >> 3, e = blockIdx.x & 7;
  int p = threadIdx.x;
  if (p >= P_) return;
  const short* wrow = (const short*)(weff + ((e * 2 + 1) * P_ + p) * D_);
  const float* arow = att + (b * E_ + e) * D_;
  const float* wprow = WpT + (e * P_ + p) * D_;
  float acc = 0.f, s2 = 0.f;
  for (int m = 0; m < D_; m += 8) {
    short8 w8 = *(const short8*)(wrow + m);
    float4 a0 = *(const float4*)(arow + m);
    float4 a1 = *(const float4*)(arow + m + 4);
    float4 q0 = *(const float4*)(wprow + m);
    float4 q1 = *(const float4*)(wprow + m + 4);
    acc = fmaf(a0.x, b2f(w8[0]), acc); acc = fmaf(a0.y, b2f(w8[1]), acc);
    acc = fmaf(a0.z, b2f(w8[2]), acc); acc = fmaf(a0.w, b2f(w8[3]), acc);
    acc = fmaf(a1.x, b2f(w8[4]), acc); acc = fmaf(a1.y, b2f(w8[5]), acc);
    acc = fmaf(a1.z, b2f(w8[6]), acc); acc = fmaf(a1.w, b2f(w8[7]), acc);
    s2 += q0.x + q0.y + q0.z + q0.w + q1.x + q1.y + q1.z + q1.w;
  }
  zc[(b * E_ + e) * P_ + p] = acc + bc[e] * s2 + bp[e * P_ + p];
}

// grouped final GEMM: out[t,p] = x[t]·weff[e,0,:,p] + zc[b(t),e,p]  via bf16 MFMA
__global__ __launch_bounds__(64) void k_final(const float* __restrict__ x,
        const __hip_bfloat16* __restrict__ weff, const float* __restrict__ zc,
        const int* __restrict__ cnt, const int* __restrict__ tok,
        float* __restrict__ out) {
  __shared__ __align__(16) unsigned short xsb[32 * 520];
  __shared__ int toks[32];
  int e = blockIdx.y, g = blockIdx.x;
  int cnt_e = cnt[e * 32];
  int base = g * 32;
  if (base >= cnt_e) return;
  int cl = cnt_e - base; if (cl > 32) cl = 32;
  int lane = threadIdx.x;
  if (lane < 32) toks[lane] = (lane < cl) ? tok[e * BN + base + lane] : 0;
  __syncthreads();
  for (int idx = lane; idx < 32 * 128; idx += 64) {
    int r = idx >> 7, c4 = (idx & 127) * 4;
    float4 v = {0.f, 0.f, 0.f, 0.f};
    if (r < cl) v = *(const float4*)(x + toks[r] * D_ + c4);
    ushort4 u4;
    u4.x = f2b(v.x); u4.y = f2b(v.y); u4.z = f2b(v.z); u4.w = f2b(v.w);
    *(ushort4*)(xsb + r * 520 + c4) = u4;
  }
  __syncthreads();
  int m16 = lane & 15, quad = lane >> 4;
  const short* w0 = (const short*)(weff + (e * 2 + 0) * P_ * D_);
  f32x4 acc[2][6];
#pragma unroll
  for (int a = 0; a < 2; ++a)
#pragma unroll
    for (int cc = 0; cc < 6; ++cc) acc[a][cc] = (f32x4){0.f, 0.f, 0.f, 0.f};
  for (int kt = 0; kt < 16; ++kt) {
    int koff = kt * 32 + quad * 8;
    short8 a0 = *(const short8*)((const short*)xsb + (m16) * 520 + koff);
    short8 a1 = *(const short8*)((const short*)xsb + (16 + m16) * 520 + koff);
#pragma unroll
    for (int nt = 0; nt < 6; ++nt) {
      short8 bf = *(const short8*)(w0 + (nt * 16 + m16) * D_ + koff);
      acc[0][nt] = __builtin_amdgcn_mfma_f32_16x16x32_bf16(a0, bf, acc[0][nt], 0, 0, 0);
      acc[1][nt] = __builtin_amdgcn_mfma_f32_16x16x32_bf16(a1, bf, acc[1][nt], 0, 0, 0);
    }
  }
#pragma unroll
  for (int mt = 0; mt < 2; ++mt)
#pragma unroll
    for (int nt = 0; nt < 6; ++nt)
#pragma unroll
      for (int rr = 0; rr < 4; ++rr) {
        int row = mt * 16 + quad * 4 + rr;
        if (row < cl) {
          int tg = toks[row];
          int bb = tg >> 9;
          int p = nt * 16 + m16;
          out[tg * P_ + p] = acc[mt][nt][rr] + zc[(bb * E_ + e) * P_ + p];
        }
      }
}

extern "C" void kernel_launch(void* const* d_in, const int* in_sizes, int n_in,
                              void* d_out, int out_size, void* d_ws, size_t ws_size,
                              hipStream_t stream) {
  const float* x      = (const float*)d_in[0];
  const float* router = (const float*)d_in[1];
  const float* Wq     = (const float*)d_in[2];
  const float* bq     = (const float*)d_in[3];
  const float* Wk     = (const float*)d_in[4];
  const float* bk     = (const float*)d_in[5];
  const float* Wv     = (const float*)d_in[6];
  const float* bv     = (const float*)d_in[7];
  const float* Wo     = (const float*)d_in[8];
  const float* bo     = (const float*)d_in[9];
  const float* Wc     = (const float*)d_in[10];
  const float* bc     = (const float*)d_in[11];
  const float* Wp     = (const float*)d_in[12];
  const float* bp     = (const float*)d_in[13];
  float* out = (float*)d_out;
  float* w = (float*)d_ws;

  float* q    = w + OQ;
  float* M    = w + OM;
  float* c    = w + OC;
  float* A0   = w + OA;
  float* A1   = w + OA + B_ * HE * N_;
  float* u    = w + OU;
  float* ap   = w + OAP;
  float* att  = w + OATT;
  float* WpT  = w + OWPT;
  float* zc   = w + OZC;
  int*   cnt  = (int*)(w + OCNT);
  int*   tok  = (int*)(w + OTOK);
  __hip_bfloat16* weff = (__hip_bfloat16*)(w + OWEFF);
  float* up   = w + OUP;

  hipMemsetAsync(cnt, 0, 256 * sizeof(int), stream);
  k_q<<<2, 256, 0, stream>>>(router, Wq, bq, q);
  k_m<<<64, 256, 0, stream>>>(Wk, bk, q, M, c);
  k_logits<<<1024, 256, 0, stream>>>(x, M, A0);
  k_softmax<<<1024, 256, 0, stream>>>(A0, A1, c);
  k_u2<<<dim3(8, 32), 512, 0, stream>>>(x, A0, up);
  k_ured<<<512, 256, 0, stream>>>(up, u);
  k_attpre<<<128, 256, 0, stream>>>(u, Wv, bv, ap);
  k_att<<<128, 256, 0, stream>>>(ap, Wo, bo, att);
  k_wpt<<<64, 256, 0, stream>>>(Wp, WpT);
  k_weff<<<3072, 256, 0, stream>>>(Wc, WpT, weff);
  k_route2<<<512, 256, 0, stream>>>(x, att, cnt, tok);
  k_zc<<<256, 128, 0, stream>>>(att, weff, WpT, bc, bp, zc);
  k_final<<<dim3(512, 8), 64, 0, stream>>>(x, weff, zc, cnt, tok, out);
}

// Round 3
// 295.418 us; speedup vs baseline: 1.4897x; 1.1394x over previous
//
#include <hip/hip_runtime.h>
#include <hip/hip_bf16.h>

#define B_ 32
#define N_ 512
#define D_ 512
#define E_ 8
#define P_ 96
#define KC 25
#define H_ 4
#define DK 128
#define HE 32
#define BN 16384

typedef short short8 __attribute__((ext_vector_type(8)));
typedef float f32x4 __attribute__((ext_vector_type(4)));

// ws offsets (in floats)
#define OQ    0
#define OM    4096
#define OC    20480
#define OA    20736      /* 2 x 524288 partial logits -> softmaxed A in first half */
#define OU    1069312    /* 524288 */
#define OAP   1593600    /* 131072 */
#define OATT  1724672    /* 131072 */
#define OWPT  1855744    /* 393216 */
#define OZC   2248960    /* 24576 */
#define OCNT  2273536    /* 256 ints (8 counters strided by 32) */
#define OTOK  2273792    /* 131072 ints */
#define OWEFF 2404864    /* 786432 bf16 = 393216 float slots */
#define OUP   2798080    /* 4194304 floats: u partials [b][nq][32][512] */

__device__ __forceinline__ float b2f(short s) {
  unsigned u = ((unsigned)(unsigned short)s) << 16;
  return __builtin_bit_cast(float, u);
}
__device__ __forceinline__ unsigned short f2b(float f) {
  return __builtin_bit_cast(unsigned short, __float2bfloat16(f));
}

// q[e][i] = router[e]·Wq[:,i] + bq[i]  — partial-sum version, 64 blocks.
// grid: iblk = bid&7 (64 cols), dblk = bid>>3 (64 d-rows). q pre-zeroed.
__global__ __launch_bounds__(256) void k_q(const float* __restrict__ router,
        const float* __restrict__ Wq, const float* __restrict__ bq,
        float* __restrict__ q) {
  __shared__ float rs[8][64];
  int iblk = blockIdx.x & 7, dblk = blockIdx.x >> 3;
  int i = iblk * 64 + (threadIdx.x & 63);
  int eg = threadIdx.x >> 6;  // 0..3 -> experts {2eg, 2eg+1}
  for (int idx = threadIdx.x; idx < 512; idx += 256) {
    int e = idx >> 6, d = idx & 63;
    rs[e][d] = router[e * D_ + dblk * 64 + d];
  }
  __syncthreads();
  float a0 = 0.f, a1 = 0.f;
  const float* wp = Wq + dblk * 64 * D_ + i;
#pragma unroll 8
  for (int d = 0; d < 64; ++d) {
    float w = wp[d * D_];
    a0 = fmaf(rs[eg * 2][d], w, a0);
    a1 = fmaf(rs[eg * 2 + 1][d], w, a1);
  }
  if (dblk == 0) { float b = bq[i]; a0 += b; a1 += b; }
  atomicAdd(&q[(eg * 2) * D_ + i], a0);
  atomicAdd(&q[(eg * 2 + 1) * D_ + i], a1);
}

// M[he][d0] = sum_j Wk[d0, h*128+j] * q[e, h*128+j];  c[he] = q[e,h-blk]·bk[h-blk]
__global__ __launch_bounds__(256) void k_m(const float* __restrict__ Wk,
        const float* __restrict__ bk, const float* __restrict__ q,
        float* __restrict__ M, float* __restrict__ c) {
  int he = blockIdx.x >> 1;
  int ch = blockIdx.x & 1;
  int d0 = ch * 256 + threadIdx.x;
  int h = he >> 3, e = he & 7;
  const float* qrow = q + e * D_ + h * DK;
  const float* wrow = Wk + d0 * D_ + h * DK;
  float acc = 0.f;
  for (int j = 0; j < DK; j += 4) {
    float4 wv = *(const float4*)(wrow + j);
    float4 qv = *(const float4*)(qrow + j);
    acc = fmaf(wv.x, qv.x, acc); acc = fmaf(wv.y, qv.y, acc);
    acc = fmaf(wv.z, qv.z, acc); acc = fmaf(wv.w, qv.w, acc);
  }
  M[he * D_ + d0] = acc;
  if (ch == 0 && threadIdx.x == 0) {
    float cc = 0.f;
    for (int j = 0; j < DK; ++j) cc = fmaf(qrow[j], bk[h * DK + j], cc);
    c[he] = cc;
  }
}

// partial logits (raw dot over a d-half): Apart[dh][b][he][n] = x[b,n,dh-half]·M[he,dh-half]
__global__ __launch_bounds__(256) void k_logits(const float* __restrict__ x,
        const float* __restrict__ M, float* __restrict__ Apart) {
  __shared__ float xs[32 * 257];
  int dh = blockIdx.x & 1;
  int nt = (blockIdx.x >> 1) & 15;
  int b = blockIdx.x >> 5;
  const float* xb = x + (b * N_ + nt * 32) * D_ + dh * 256;
  for (int idx = threadIdx.x; idx < 32 * 256; idx += 256) {
    int r = idx >> 8, cc = idx & 255;
    xs[r * 257 + cc] = xb[r * D_ + cc];
  }
  __syncthreads();
  int n = threadIdx.x & 31, heg = threadIdx.x >> 5;
  const float* xr = xs + n * 257;
  float acc[4] = {0.f, 0.f, 0.f, 0.f};
  for (int d = 0; d < 256; d += 4) {
    float x0 = xr[d], x1 = xr[d + 1], x2 = xr[d + 2], x3 = xr[d + 3];
#pragma unroll
    for (int i = 0; i < 4; ++i) {
      float4 mv = *(const float4*)(M + (heg + 8 * i) * D_ + dh * 256 + d);
      acc[i] = fmaf(x0, mv.x, acc[i]);
      acc[i] = fmaf(x1, mv.y, acc[i]);
      acc[i] = fmaf(x2, mv.z, acc[i]);
      acc[i] = fmaf(x3, mv.w, acc[i]);
    }
  }
  int ncol = nt * 32 + n;
  float* Ad = Apart + dh * (B_ * HE * N_);
#pragma unroll
  for (int i = 0; i < 4; ++i)
    Ad[(b * HE + heg + 8 * i) * N_ + ncol] = acc[i];
}

// softmax over n per (b,he) row; combines d-half partials, applies scale and c[he]
__global__ __launch_bounds__(256) void k_softmax(float* __restrict__ A0,
        const float* __restrict__ A1, const float* __restrict__ c) {
  int row = blockIdx.x;
  float* p0 = A0 + row * N_;
  const float* p1 = A1 + row * N_;
  float cc = c[row & 31];
  int t = threadIdx.x;
  const float scale = 0.08838834764831845f;
  float v0 = scale * (p0[t] + p1[t] + cc);
  float v1 = scale * (p0[t + 256] + p1[t + 256] + cc);
  __shared__ float red[4], red2[4];
  float m = fmaxf(v0, v1);
#pragma unroll
  for (int off = 32; off; off >>= 1) m = fmaxf(m, __shfl_xor(m, off));
  if ((t & 63) == 0) red[t >> 6] = m;
  __syncthreads();
  m = fmaxf(fmaxf(red[0], red[1]), fmaxf(red[2], red[3]));
  float e0 = expf(v0 - m), e1 = expf(v1 - m);
  float s = e0 + e1;
#pragma unroll
  for (int off = 32; off; off >>= 1) s += __shfl_xor(s, off);
  if ((t & 63) == 0) red2[t >> 6] = s;
  __syncthreads();
  s = red2[0] + red2[1] + red2[2] + red2[3];
  float inv = 1.0f / s;
  p0[t] = e0 * inv;
  p0[t + 256] = e1 * inv;
}

// u partials over n-slices: up[b][nq][he][d] = sum_{n in slice} A[b,he,n]*x[b,n,d]
__global__ __launch_bounds__(512) void k_u2(const float* __restrict__ x,
        const float* __restrict__ A, float* __restrict__ up) {
  __shared__ float As[64 * 33];
  int nq = blockIdx.x, b = blockIdx.y;
  for (int idx = threadIdx.x; idx < 64 * 32; idx += 512) {
    int n = idx & 63, he = idx >> 6;
    As[n * 33 + he] = A[(b * HE + he) * N_ + nq * 64 + n];
  }
  __syncthreads();
  int dq = threadIdx.x & 127, hg = threadIdx.x >> 7;  // hg uniform per wave
  const float* xb = x + (b * N_ + nq * 64) * D_ + dq * 4;
  float acc[8][4];
#pragma unroll
  for (int j = 0; j < 8; ++j)
#pragma unroll
    for (int k = 0; k < 4; ++k) acc[j][k] = 0.f;
  for (int n = 0; n < 64; ++n) {
    float4 xv = *(const float4*)(xb + n * D_);
    const float* ar = As + n * 33 + hg * 8;
#pragma unroll
    for (int j = 0; j < 8; ++j) {
      float a = ar[j];
      acc[j][0] = fmaf(a, xv.x, acc[j][0]);
      acc[j][1] = fmaf(a, xv.y, acc[j][1]);
      acc[j][2] = fmaf(a, xv.z, acc[j][2]);
      acc[j][3] = fmaf(a, xv.w, acc[j][3]);
    }
  }
  float* o = up + (((b * 8 + nq) * HE) + hg * 8) * D_ + dq * 4;
#pragma unroll
  for (int j = 0; j < 8; ++j) {
    float4 v; v.x = acc[j][0]; v.y = acc[j][1]; v.z = acc[j][2]; v.w = acc[j][3];
    *(float4*)(o + j * D_) = v;
  }
}

// u[b][he][d] = sum_nq up[b][nq][he][d]
__global__ __launch_bounds__(256) void k_ured(const float* __restrict__ up,
        float* __restrict__ u) {
  int o4 = (blockIdx.x * 256 + threadIdx.x) * 4;
  int bhe = o4 >> 9, d = o4 & 511;
  int b = bhe >> 5, he = bhe & 31;
  float4 s = {0.f, 0.f, 0.f, 0.f};
#pragma unroll
  for (int nq = 0; nq < 8; ++nq) {
    float4 v = *(const float4*)(up + (((b * 8 + nq) * HE + he) << 9) + d);
    s.x += v.x; s.y += v.y; s.z += v.z; s.w += v.w;
  }
  *(float4*)(u + o4) = s;
}

// att_pre[b][e][i] = sum_d u[b, h(i)*8+e, d] * Wv[d,i] + bv[i]   (h(i)=i>>7)
__global__ __launch_bounds__(256) void k_attpre(const float* __restrict__ u,
        const float* __restrict__ Wv, const float* __restrict__ bv,
        float* __restrict__ ap) {
  __shared__ float us[8 * D_];
  int e = blockIdx.x & 7;
  int ic = (blockIdx.x >> 3) & 3;
  int bq = blockIdx.x >> 5;
  for (int idx = threadIdx.x; idx < 8 * D_; idx += 256) {
    int rr = idx >> 9, d = idx & 511;
    us[idx] = u[((bq * 8 + rr) * HE + ic * 8 + e) * D_ + d];
  }
  __syncthreads();
  int i = ic * 128 + (threadIdx.x & 127);
  int bg = threadIdx.x >> 7;
  const float* usb = us + bg * 4 * D_;
  float acc[4] = {0.f, 0.f, 0.f, 0.f};
  for (int d = 0; d < D_; d += 4) {
    float w0 = Wv[(d + 0) * D_ + i];
    float w1 = Wv[(d + 1) * D_ + i];
    float w2 = Wv[(d + 2) * D_ + i];
    float w3 = Wv[(d + 3) * D_ + i];
#pragma unroll
    for (int r = 0; r < 4; ++r) {
      float4 uv = *(const float4*)(usb + r * D_ + d);
      float s = acc[r];
      s = fmaf(uv.x, w0, s); s = fmaf(uv.y, w1, s);
      s = fmaf(uv.z, w2, s); s = fmaf(uv.w, w3, s);
      acc[r] = s;
    }
  }
  float bvi = bv[i];
#pragma unroll
  for (int r = 0; r < 4; ++r)
    ap[((bq * 8 + bg * 4 + r) * E_ + e) * D_ + i] = acc[r] + bvi;
}

// att[b][e][o] = sum_i ap[b,e,i] * Wo[i,o] + bo[o]
__global__ __launch_bounds__(256) void k_att(const float* __restrict__ ap,
        const float* __restrict__ Wo, const float* __restrict__ bo,
        float* __restrict__ att) {
  __shared__ float ps[8 * D_];
  int b = blockIdx.x >> 2, oc = blockIdx.x & 3;
  for (int idx = threadIdx.x; idx < 8 * D_; idx += 256)
    ps[idx] = ap[b * E_ * D_ + idx];
  __syncthreads();
  int o = oc * 128 + (threadIdx.x & 127);
  int eg = threadIdx.x >> 7;
  const float* pe = ps + eg * 4 * D_;
  float acc[4] = {0.f, 0.f, 0.f, 0.f};
  for (int i2 = 0; i2 < D_; i2 += 4) {
    float w0 = Wo[(i2 + 0) * D_ + o];
    float w1 = Wo[(i2 + 1) * D_ + o];
    float w2 = Wo[(i2 + 2) * D_ + o];
    float w3 = Wo[(i2 + 3) * D_ + o];
#pragma unroll
    for (int r = 0; r < 4; ++r) {
      float4 pv = *(const float4*)(pe + r * D_ + i2);
      float s = acc[r];
      s = fmaf(pv.x, w0, s); s = fmaf(pv.y, w1, s);
      s = fmaf(pv.z, w2, s); s = fmaf(pv.w, w3, s);
      acc[r] = s;
    }
  }
  float boo = bo[o];
#pragma unroll
  for (int r = 0; r < 4; ++r)
    att[(b * E_ + eg * 4 + r) * D_ + o] = acc[r] + boo;
}

// WpT[e][p][l] = Wp[e][l][p]
__global__ __launch_bounds__(256) void k_wpt(const float* __restrict__ Wp,
        float* __restrict__ WpT) {
  __shared__ float tile[64 * 97];
  int e = blockIdx.x >> 3, lt = blockIdx.x & 7;
  for (int idx = threadIdx.x; idx < 64 * 96; idx += 256) {
    int l = idx / 96, p = idx - l * 96;
    tile[l * 97 + p] = Wp[(e * D_ + lt * 64 + l) * P_ + p];
  }
  __syncthreads();
  for (int idx = threadIdx.x; idx < 96 * 64; idx += 256) {
    int p = idx >> 6, l = idx & 63;
    WpT[(e * P_ + p) * D_ + lt * 64 + l] = tile[l * 97 + p];
  }
}

// weff (bf16) [e][j][p][m] = sum_k Wc[e,j,k] * Wp[e, m-k+12, p]
__global__ __launch_bounds__(256) void k_weff(const float* __restrict__ Wc,
        const float* __restrict__ WpT, __hip_bfloat16* __restrict__ weff) {
  int flat = blockIdx.x * 256 + threadIdx.x;
  int m = flat & 511;
  int rest = flat >> 9;       // (e*2+j)*96 + p
  int p = rest % 96;
  int ej = rest / 96;
  int e = ej >> 1, j = ej & 1;
  const float* wprow = WpT + (e * P_ + p) * D_;
  const float* wc = Wc + (e * 2 + j) * KC;
  float acc = 0.f;
#pragma unroll
  for (int k = 0; k < KC; ++k) {
    int l = m - k + 12;
    if (l >= 0 && l < D_) acc = fmaf(wc[k], wprow[l], acc);
  }
  weff[flat] = __float2bfloat16(acc);
}

// routing v2: one wave per token. score[e] = att[b,e]·x[b,n] / ||att[b,e]||,
// argmax -> per-block expert lists -> one global atomic per (block,expert).
__global__ __launch_bounds__(256) void k_route2(const float* __restrict__ x,
        const float* __restrict__ att, int* __restrict__ cnt,
        int* __restrict__ tok) {
  __shared__ float att_s[8 * D_];
  __shared__ float rn[8];
  __shared__ float red[4][520];
  __shared__ int blist[8][32];
  __shared__ int bcnt[8];
  int b = blockIdx.x >> 4, tile = blockIdx.x & 15;
  for (int idx = threadIdx.x; idx < 1024; idx += 256)
    *(float4*)(att_s + idx * 4) = *(const float4*)(att + b * E_ * D_ + idx * 4);
  if (threadIdx.x < 8) bcnt[threadIdx.x] = 0;
  __syncthreads();
  {
    int e = threadIdx.x >> 5, l = threadIdx.x & 31;
    float s = 0.f;
    for (int d0 = l; d0 < D_; d0 += 32) {
      float v = att_s[e * D_ + d0];
      s = fmaf(v, v, s);
    }
#pragma unroll
    for (int off = 16; off; off >>= 1) s += __shfl_xor(s, off);
    if (l == 0) rn[e] = 1.0f / sqrtf(s);
  }
  __syncthreads();
  int w = threadIdx.x >> 6, lane = threadIdx.x & 63;
  int e2 = lane & 7, ch = lane >> 3;
  float* rw = red[w];
  for (int i = 0; i < 8; ++i) {
    int t = b * N_ + tile * 32 + w * 8 + i;
    const float* xp = x + t * D_ + lane * 8;
    float4 xa = *(const float4*)xp;
    float4 xb4 = *(const float4*)(xp + 4);
    float p[8];
#pragma unroll
    for (int e = 0; e < 8; ++e) {
      const float* apt = att_s + e * D_ + lane * 8;
      float4 a0 = *(const float4*)apt;
      float4 a1 = *(const float4*)(apt + 4);
      float s = a0.x * xa.x;
      s = fmaf(a0.y, xa.y, s); s = fmaf(a0.z, xa.z, s); s = fmaf(a0.w, xa.w, s);
      s = fmaf(a1.x, xb4.x, s); s = fmaf(a1.y, xb4.y, s);
      s = fmaf(a1.z, xb4.z, s); s = fmaf(a1.w, xb4.w, s);
      p[e] = s;
    }
#pragma unroll
    for (int e = 0; e < 8; ++e) rw[e * 65 + lane] = p[e];
    float s = 0.f;
#pragma unroll
    for (int k = 0; k < 8; ++k) s += rw[e2 * 65 + ch * 8 + k];
    s += __shfl_xor(s, 8); s += __shfl_xor(s, 16); s += __shfl_xor(s, 32);
    float sc = s * rn[e2];
    int be = e2;
#pragma unroll
    for (int off = 1; off < 8; off <<= 1) {
      float o = __shfl_xor(sc, off);
      int oe = __shfl_xor(be, off);
      if (o > sc || (o == sc && oe < be)) { sc = o; be = oe; }
    }
    if (lane == 0) {
      int slot = atomicAdd(&bcnt[be], 1);
      blist[be][slot] = t;
    }
  }
  __syncthreads();
  int e = threadIdx.x >> 5, r = threadIdx.x & 31;
  int ce = bcnt[e];
  int gs = 0;
  if (r == 0 && ce > 0) gs = atomicAdd(&cnt[e * 32], ce);
  gs = __shfl(gs, (threadIdx.x & 63) & 32);
  for (int k2 = r; k2 < ce; k2 += 32) tok[e * BN + gs + k2] = blist[e][k2];
}

// zc[b][e][p] = att[b,e]·weff[e,1,:,p] + bc[e]*sum_l Wp[e,l,p] + bp[e,p]
__global__ __launch_bounds__(128) void k_zc(const float* __restrict__ att,
        const __hip_bfloat16* __restrict__ weff, const float* __restrict__ WpT,
        const float* __restrict__ bc, const float* __restrict__ bp,
        float* __restrict__ zc) {
  int b = blockIdx.x >> 3, e = blockIdx.x & 7;
  int p = threadIdx.x;
  if (p >= P_) return;
  const short* wrow = (const short*)(weff + ((e * 2 + 1) * P_ + p) * D_);
  const float* arow = att + (b * E_ + e) * D_;
  const float* wprow = WpT + (e * P_ + p) * D_;
  float acc = 0.f, s2 = 0.f;
  for (int m = 0; m < D_; m += 8) {
    short8 w8 = *(const short8*)(wrow + m);
    float4 a0 = *(const float4*)(arow + m);
    float4 a1 = *(const float4*)(arow + m + 4);
    float4 q0 = *(const float4*)(wprow + m);
    float4 q1 = *(const float4*)(wprow + m + 4);
    acc = fmaf(a0.x, b2f(w8[0]), acc); acc = fmaf(a0.y, b2f(w8[1]), acc);
    acc = fmaf(a0.z, b2f(w8[2]), acc); acc = fmaf(a0.w, b2f(w8[3]), acc);
    acc = fmaf(a1.x, b2f(w8[4]), acc); acc = fmaf(a1.y, b2f(w8[5]), acc);
    acc = fmaf(a1.z, b2f(w8[6]), acc); acc = fmaf(a1.w, b2f(w8[7]), acc);
    s2 += q0.x + q0.y + q0.z + q0.w + q1.x + q1.y + q1.z + q1.w;
  }
  zc[(b * E_ + e) * P_ + p] = acc + bc[e] * s2 + bp[e * P_ + p];
}

// grouped final GEMM: out[t,p] = x[t]·weff[e,0,:,p] + zc[b(t),e,p]  via bf16 MFMA
__global__ __launch_bounds__(64) void k_final(const float* __restrict__ x,
        const __hip_bfloat16* __restrict__ weff, const float* __restrict__ zc,
        const int* __restrict__ cnt, const int* __restrict__ tok,
        float* __restrict__ out) {
  __shared__ __align__(16) unsigned short xsb[32 * 520];
  __shared__ int toks[32];
  int e = blockIdx.y, g = blockIdx.x;
  int cnt_e = cnt[e * 32];
  int base = g * 32;
  if (base >= cnt_e) return;
  int cl = cnt_e - base; if (cl > 32) cl = 32;
  int lane = threadIdx.x;
  if (lane < 32) toks[lane] = (lane < cl) ? tok[e * BN + base + lane] : 0;
  __syncthreads();
  for (int idx = lane; idx < 32 * 128; idx += 64) {
    int r = idx >> 7, c4 = (idx & 127) * 4;
    float4 v = {0.f, 0.f, 0.f, 0.f};
    if (r < cl) v = *(const float4*)(x + toks[r] * D_ + c4);
    ushort4 u4;
    u4.x = f2b(v.x); u4.y = f2b(v.y); u4.z = f2b(v.z); u4.w = f2b(v.w);
    *(ushort4*)(xsb + r * 520 + c4) = u4;
  }
  __syncthreads();
  int m16 = lane & 15, quad = lane >> 4;
  const short* w0 = (const short*)(weff + (e * 2 + 0) * P_ * D_);
  f32x4 acc[2][6];
#pragma unroll
  for (int a = 0; a < 2; ++a)
#pragma unroll
    for (int cc = 0; cc < 6; ++cc) acc[a][cc] = (f32x4){0.f, 0.f, 0.f, 0.f};
  for (int kt = 0; kt < 16; ++kt) {
    int koff = kt * 32 + quad * 8;
    short8 a0 = *(const short8*)((const short*)xsb + (m16) * 520 + koff);
    short8 a1 = *(const short8*)((const short*)xsb + (16 + m16) * 520 + koff);
#pragma unroll
    for (int nt = 0; nt < 6; ++nt) {
      short8 bf = *(const short8*)(w0 + (nt * 16 + m16) * D_ + koff);
      acc[0][nt] = __builtin_amdgcn_mfma_f32_16x16x32_bf16(a0, bf, acc[0][nt], 0, 0, 0);
      acc[1][nt] = __builtin_amdgcn_mfma_f32_16x16x32_bf16(a1, bf, acc[1][nt], 0, 0, 0);
    }
  }
#pragma unroll
  for (int mt = 0; mt < 2; ++mt)
#pragma unroll
    for (int nt = 0; nt < 6; ++nt)
#pragma unroll
      for (int rr = 0; rr < 4; ++rr) {
        int row = mt * 16 + quad * 4 + rr;
        if (row < cl) {
          int tg = toks[row];
          int bb = tg >> 9;
          int p = nt * 16 + m16;
          out[tg * P_ + p] = acc[mt][nt][rr] + zc[(bb * E_ + e) * P_ + p];
        }
      }
}

extern "C" void kernel_launch(void* const* d_in, const int* in_sizes, int n_in,
                              void* d_out, int out_size, void* d_ws, size_t ws_size,
                              hipStream_t stream) {
  const float* x      = (const float*)d_in[0];
  const float* router = (const float*)d_in[1];
  const float* Wq     = (const float*)d_in[2];
  const float* bq     = (const float*)d_in[3];
  const float* Wk     = (const float*)d_in[4];
  const float* bk     = (const float*)d_in[5];
  const float* Wv     = (const float*)d_in[6];
  const float* bv     = (const float*)d_in[7];
  const float* Wo     = (const float*)d_in[8];
  const float* bo     = (const float*)d_in[9];
  const float* Wc     = (const float*)d_in[10];
  const float* bc     = (const float*)d_in[11];
  const float* Wp     = (const float*)d_in[12];
  const float* bp     = (const float*)d_in[13];
  float* out = (float*)d_out;
  float* w = (float*)d_ws;

  float* q    = w + OQ;
  float* M    = w + OM;
  float* c    = w + OC;
  float* A0   = w + OA;
  float* A1   = w + OA + B_ * HE * N_;
  float* u    = w + OU;
  float* ap   = w + OAP;
  float* att  = w + OATT;
  float* WpT  = w + OWPT;
  float* zc   = w + OZC;
  int*   cnt  = (int*)(w + OCNT);
  int*   tok  = (int*)(w + OTOK);
  __hip_bfloat16* weff = (__hip_bfloat16*)(w + OWEFF);
  float* up   = w + OUP;

  hipMemsetAsync(w + OQ, 0, 4096 * sizeof(float), stream);
  hipMemsetAsync(cnt, 0, 256 * sizeof(int), stream);
  k_q<<<64, 256, 0, stream>>>(router, Wq, bq, q);
  k_m<<<64, 256, 0, stream>>>(Wk, bk, q, M, c);
  k_logits<<<1024, 256, 0, stream>>>(x, M, A0);
  k_softmax<<<1024, 256, 0, stream>>>(A0, A1, c);
  k_u2<<<dim3(8, 32), 512, 0, stream>>>(x, A0, up);
  k_ured<<<512, 256, 0, stream>>>(up, u);
  k_attpre<<<128, 256, 0, stream>>>(u, Wv, bv, ap);
  k_att<<<128, 256, 0, stream>>>(ap, Wo, bo, att);
  k_wpt<<<64, 256, 0, stream>>>(Wp, WpT);
  k_weff<<<3072, 256, 0, stream>>>(Wc, WpT, weff);
  k_route2<<<512, 256, 0, stream>>>(x, att, cnt, tok);
  k_zc<<<256, 128, 0, stream>>>(att, weff, WpT, bc, bp, zc);
  k_final<<<dim3(512, 8), 64, 0, stream>>>(x, weff, zc, cnt, tok, out);
}

// Round 4
// 274.766 us; speedup vs baseline: 1.6017x; 1.0752x over previous
//
#include <hip/hip_runtime.h>
#include <hip/hip_bf16.h>

#define B_ 32
#define N_ 512
#define D_ 512
#define E_ 8
#define P_ 96
#define KC 25
#define H_ 4
#define DK 128
#define HE 32
#define BN 16384

typedef short short8 __attribute__((ext_vector_type(8)));
typedef float f32x4 __attribute__((ext_vector_type(4)));

// ws offsets (in floats)
#define OQ    0
#define OM    4096
#define OC    20480
#define OA    20736      /* 2 x 524288 partial logits -> softmaxed A in first half */
#define OU    1069312    /* 524288 */
#define OAP   1593600    /* 131072 */
#define OATT  1724672    /* 131072 */
#define OWPT  1855744    /* 393216 */
#define OZC   2248960    /* 24576 */
#define OCNT  2273536    /* 256 ints (8 counters strided by 32) */
#define OTOK  2273792    /* 131072 ints */
#define OWEFF 2404864    /* 786432 bf16 = 393216 float slots */
#define OUP   2798080    /* 4194304 floats: u partials [b][nq][32][512] */

__device__ __forceinline__ float b2f(short s) {
  unsigned u = ((unsigned)(unsigned short)s) << 16;
  return __builtin_bit_cast(float, u);
}
__device__ __forceinline__ unsigned short f2b(float f) {
  return __builtin_bit_cast(unsigned short, __float2bfloat16(f));
}

// q[e][i] = router[e]·Wq[:,i] + bq[i]  — partial-sum version, 64 blocks.
__global__ __launch_bounds__(256) void k_q(const float* __restrict__ router,
        const float* __restrict__ Wq, const float* __restrict__ bq,
        float* __restrict__ q) {
  __shared__ float rs[8][64];
  int iblk = blockIdx.x & 7, dblk = blockIdx.x >> 3;
  int i = iblk * 64 + (threadIdx.x & 63);
  int eg = threadIdx.x >> 6;  // 0..3 -> experts {2eg, 2eg+1}
  for (int idx = threadIdx.x; idx < 512; idx += 256) {
    int e = idx >> 6, d = idx & 63;
    rs[e][d] = router[e * D_ + dblk * 64 + d];
  }
  __syncthreads();
  float a0 = 0.f, a1 = 0.f;
  const float* wp = Wq + dblk * 64 * D_ + i;
#pragma unroll 8
  for (int d = 0; d < 64; ++d) {
    float w = wp[d * D_];
    a0 = fmaf(rs[eg * 2][d], w, a0);
    a1 = fmaf(rs[eg * 2 + 1][d], w, a1);
  }
  if (dblk == 0) { float b = bq[i]; a0 += b; a1 += b; }
  atomicAdd(&q[(eg * 2) * D_ + i], a0);
  atomicAdd(&q[(eg * 2 + 1) * D_ + i], a1);
}

// M[he][d0] = sum_j Wk[d0, h*128+j] * q[e, h*128+j];  c[he] = q[e,h-blk]·bk[h-blk]
__global__ __launch_bounds__(256) void k_m(const float* __restrict__ Wk,
        const float* __restrict__ bk, const float* __restrict__ q,
        float* __restrict__ M, float* __restrict__ c) {
  int he = blockIdx.x >> 1;
  int ch = blockIdx.x & 1;
  int d0 = ch * 256 + threadIdx.x;
  int h = he >> 3, e = he & 7;
  const float* qrow = q + e * D_ + h * DK;
  const float* wrow = Wk + d0 * D_ + h * DK;
  float acc = 0.f;
  for (int j = 0; j < DK; j += 4) {
    float4 wv = *(const float4*)(wrow + j);
    float4 qv = *(const float4*)(qrow + j);
    acc = fmaf(wv.x, qv.x, acc); acc = fmaf(wv.y, qv.y, acc);
    acc = fmaf(wv.z, qv.z, acc); acc = fmaf(wv.w, qv.w, acc);
  }
  M[he * D_ + d0] = acc;
  if (ch == 0 && threadIdx.x == 0) {
    float cc = 0.f;
    for (int j = 0; j < DK; ++j) cc = fmaf(qrow[j], bk[h * DK + j], cc);
    c[he] = cc;
  }
}

// partial logits (raw dot over a d-half): Apart[dh][b][he][n] = x[b,n,dh-half]·M[he,dh-half]
__global__ __launch_bounds__(256) void k_logits(const float* __restrict__ x,
        const float* __restrict__ M, float* __restrict__ Apart) {
  __shared__ float xs[32 * 257];
  int dh = blockIdx.x & 1;
  int nt = (blockIdx.x >> 1) & 15;
  int b = blockIdx.x >> 5;
  const float* xb = x + (b * N_ + nt * 32) * D_ + dh * 256;
  for (int idx = threadIdx.x; idx < 32 * 256; idx += 256) {
    int r = idx >> 8, cc = idx & 255;
    xs[r * 257 + cc] = xb[r * D_ + cc];
  }
  __syncthreads();
  int n = threadIdx.x & 31, heg = threadIdx.x >> 5;
  const float* xr = xs + n * 257;
  float acc[4] = {0.f, 0.f, 0.f, 0.f};
  for (int d = 0; d < 256; d += 4) {
    float x0 = xr[d], x1 = xr[d + 1], x2 = xr[d + 2], x3 = xr[d + 3];
#pragma unroll
    for (int i = 0; i < 4; ++i) {
      float4 mv = *(const float4*)(M + (heg + 8 * i) * D_ + dh * 256 + d);
      acc[i] = fmaf(x0, mv.x, acc[i]);
      acc[i] = fmaf(x1, mv.y, acc[i]);
      acc[i] = fmaf(x2, mv.z, acc[i]);
      acc[i] = fmaf(x3, mv.w, acc[i]);
    }
  }
  int ncol = nt * 32 + n;
  float* Ad = Apart + dh * (B_ * HE * N_);
#pragma unroll
  for (int i = 0; i < 4; ++i)
    Ad[(b * HE + heg + 8 * i) * N_ + ncol] = acc[i];
}

// softmax over n per (b,he) row; combines d-half partials, applies scale and c[he]
__global__ __launch_bounds__(256) void k_softmax(float* __restrict__ A0,
        const float* __restrict__ A1, const float* __restrict__ c) {
  int row = blockIdx.x;
  float* p0 = A0 + row * N_;
  const float* p1 = A1 + row * N_;
  float cc = c[row & 31];
  int t = threadIdx.x;
  const float scale = 0.08838834764831845f;
  float v0 = scale * (p0[t] + p1[t] + cc);
  float v1 = scale * (p0[t + 256] + p1[t + 256] + cc);
  __shared__ float red[4], red2[4];
  float m = fmaxf(v0, v1);
#pragma unroll
  for (int off = 32; off; off >>= 1) m = fmaxf(m, __shfl_xor(m, off));
  if ((t & 63) == 0) red[t >> 6] = m;
  __syncthreads();
  m = fmaxf(fmaxf(red[0], red[1]), fmaxf(red[2], red[3]));
  float e0 = expf(v0 - m), e1 = expf(v1 - m);
  float s = e0 + e1;
#pragma unroll
  for (int off = 32; off; off >>= 1) s += __shfl_xor(s, off);
  if ((t & 63) == 0) red2[t >> 6] = s;
  __syncthreads();
  s = red2[0] + red2[1] + red2[2] + red2[3];
  float inv = 1.0f / s;
  p0[t] = e0 * inv;
  p0[t + 256] = e1 * inv;
}

// u partials over n-slices: up[b][nq][he][d] = sum_{n in slice} A[b,he,n]*x[b,n,d]
__global__ __launch_bounds__(512) void k_u2(const float* __restrict__ x,
        const float* __restrict__ A, float* __restrict__ up) {
  __shared__ float As[64 * 33];
  int nq = blockIdx.x, b = blockIdx.y;
  for (int idx = threadIdx.x; idx < 64 * 32; idx += 512) {
    int n = idx & 63, he = idx >> 6;
    As[n * 33 + he] = A[(b * HE + he) * N_ + nq * 64 + n];
  }
  __syncthreads();
  int dq = threadIdx.x & 127, hg = threadIdx.x >> 7;  // hg uniform per wave
  const float* xb = x + (b * N_ + nq * 64) * D_ + dq * 4;
  float acc[8][4];
#pragma unroll
  for (int j = 0; j < 8; ++j)
#pragma unroll
    for (int k = 0; k < 4; ++k) acc[j][k] = 0.f;
  for (int n = 0; n < 64; ++n) {
    float4 xv = *(const float4*)(xb + n * D_);
    const float* ar = As + n * 33 + hg * 8;
#pragma unroll
    for (int j = 0; j < 8; ++j) {
      float a = ar[j];
      acc[j][0] = fmaf(a, xv.x, acc[j][0]);
      acc[j][1] = fmaf(a, xv.y, acc[j][1]);
      acc[j][2] = fmaf(a, xv.z, acc[j][2]);
      acc[j][3] = fmaf(a, xv.w, acc[j][3]);
    }
  }
  float* o = up + (((b * 8 + nq) * HE) + hg * 8) * D_ + dq * 4;
#pragma unroll
  for (int j = 0; j < 8; ++j) {
    float4 v; v.x = acc[j][0]; v.y = acc[j][1]; v.z = acc[j][2]; v.w = acc[j][3];
    *(float4*)(o + j * D_) = v;
  }
}

// u[b][he][d] = sum_nq up[b][nq][he][d]
__global__ __launch_bounds__(256) void k_ured(const float* __restrict__ up,
        float* __restrict__ u) {
  int o4 = (blockIdx.x * 256 + threadIdx.x) * 4;
  int bhe = o4 >> 9, d = o4 & 511;
  int b = bhe >> 5, he = bhe & 31;
  float4 s = {0.f, 0.f, 0.f, 0.f};
#pragma unroll
  for (int nq = 0; nq < 8; ++nq) {
    float4 v = *(const float4*)(up + (((b * 8 + nq) * HE + he) << 9) + d);
    s.x += v.x; s.y += v.y; s.z += v.z; s.w += v.w;
  }
  *(float4*)(u + o4) = s;
}

// att_pre[b][e][i] = sum_d u[b, h(i)*8+e, d] * Wv[d,i] + bv[i]   (h(i)=i>>7)
__global__ __launch_bounds__(256) void k_attpre(const float* __restrict__ u,
        const float* __restrict__ Wv, const float* __restrict__ bv,
        float* __restrict__ ap) {
  __shared__ float us[8 * D_];
  int e = blockIdx.x & 7;
  int ic = (blockIdx.x >> 3) & 3;
  int bq = blockIdx.x >> 5;
  for (int idx = threadIdx.x; idx < 8 * D_; idx += 256) {
    int rr = idx >> 9, d = idx & 511;
    us[idx] = u[((bq * 8 + rr) * HE + ic * 8 + e) * D_ + d];
  }
  __syncthreads();
  int i = ic * 128 + (threadIdx.x & 127);
  int bg = threadIdx.x >> 7;
  const float* usb = us + bg * 4 * D_;
  float acc[4] = {0.f, 0.f, 0.f, 0.f};
  for (int d = 0; d < D_; d += 4) {
    float w0 = Wv[(d + 0) * D_ + i];
    float w1 = Wv[(d + 1) * D_ + i];
    float w2 = Wv[(d + 2) * D_ + i];
    float w3 = Wv[(d + 3) * D_ + i];
#pragma unroll
    for (int r = 0; r < 4; ++r) {
      float4 uv = *(const float4*)(usb + r * D_ + d);
      float s = acc[r];
      s = fmaf(uv.x, w0, s); s = fmaf(uv.y, w1, s);
      s = fmaf(uv.z, w2, s); s = fmaf(uv.w, w3, s);
      acc[r] = s;
    }
  }
  float bvi = bv[i];
#pragma unroll
  for (int r = 0; r < 4; ++r)
    ap[((bq * 8 + bg * 4 + r) * E_ + e) * D_ + i] = acc[r] + bvi;
}

// att[b][e][o] = sum_i ap[b,e,i] * Wo[i,o] + bo[o]
__global__ __launch_bounds__(256) void k_att(const float* __restrict__ ap,
        const float* __restrict__ Wo, const float* __restrict__ bo,
        float* __restrict__ att) {
  __shared__ float ps[8 * D_];
  int b = blockIdx.x >> 2, oc = blockIdx.x & 3;
  for (int idx = threadIdx.x; idx < 8 * D_; idx += 256)
    ps[idx] = ap[b * E_ * D_ + idx];
  __syncthreads();
  int o = oc * 128 + (threadIdx.x & 127);
  int eg = threadIdx.x >> 7;
  const float* pe = ps + eg * 4 * D_;
  float acc[4] = {0.f, 0.f, 0.f, 0.f};
  for (int i2 = 0; i2 < D_; i2 += 4) {
    float w0 = Wo[(i2 + 0) * D_ + o];
    float w1 = Wo[(i2 + 1) * D_ + o];
    float w2 = Wo[(i2 + 2) * D_ + o];
    float w3 = Wo[(i2 + 3) * D_ + o];
#pragma unroll
    for (int r = 0; r < 4; ++r) {
      float4 pv = *(const float4*)(pe + r * D_ + i2);
      float s = acc[r];
      s = fmaf(pv.x, w0, s); s = fmaf(pv.y, w1, s);
      s = fmaf(pv.z, w2, s); s = fmaf(pv.w, w3, s);
      acc[r] = s;
    }
  }
  float boo = bo[o];
#pragma unroll
  for (int r = 0; r < 4; ++r)
    att[(b * E_ + eg * 4 + r) * D_ + o] = acc[r] + boo;
}

// WpT[e][p][l] = Wp[e][l][p]
__global__ __launch_bounds__(256) void k_wpt(const float* __restrict__ Wp,
        float* __restrict__ WpT) {
  __shared__ float tile[64 * 97];
  int e = blockIdx.x >> 3, lt = blockIdx.x & 7;
  for (int idx = threadIdx.x; idx < 64 * 96; idx += 256) {
    int l = idx / 96, p = idx - l * 96;
    tile[l * 97 + p] = Wp[(e * D_ + lt * 64 + l) * P_ + p];
  }
  __syncthreads();
  for (int idx = threadIdx.x; idx < 96 * 64; idx += 256) {
    int p = idx >> 6, l = idx & 63;
    WpT[(e * P_ + p) * D_ + lt * 64 + l] = tile[l * 97 + p];
  }
}

// weff (bf16) [e][j][p][m] = sum_k Wc[e,j,k] * Wp[e, m-k+12, p]
__global__ __launch_bounds__(256) void k_weff(const float* __restrict__ Wc,
        const float* __restrict__ WpT, __hip_bfloat16* __restrict__ weff) {
  int flat = blockIdx.x * 256 + threadIdx.x;
  int m = flat & 511;
  int rest = flat >> 9;       // (e*2+j)*96 + p
  int p = rest % 96;
  int ej = rest / 96;
  int e = ej >> 1, j = ej & 1;
  const float* wprow = WpT + (e * P_ + p) * D_;
  const float* wc = Wc + (e * 2 + j) * KC;
  float acc = 0.f;
#pragma unroll
  for (int k = 0; k < KC; ++k) {
    int l = m - k + 12;
    if (l >= 0 && l < D_) acc = fmaf(wc[k], wprow[l], acc);
  }
  weff[flat] = __float2bfloat16(acc);
}

// routing v2: one wave per token. score[e] = att[b,e]·x[b,n] / ||att[b,e]||,
// argmax -> per-block expert lists -> one global atomic per (block,expert).
__global__ __launch_bounds__(256) void k_route2(const float* __restrict__ x,
        const float* __restrict__ att, int* __restrict__ cnt,
        int* __restrict__ tok) {
  __shared__ float att_s[8 * D_];
  __shared__ float rn[8];
  __shared__ float red[4][520];
  __shared__ int blist[8][32];
  __shared__ int bcnt[8];
  int b = blockIdx.x >> 4, tile = blockIdx.x & 15;
  for (int idx = threadIdx.x; idx < 1024; idx += 256)
    *(float4*)(att_s + idx * 4) = *(const float4*)(att + b * E_ * D_ + idx * 4);
  if (threadIdx.x < 8) bcnt[threadIdx.x] = 0;
  __syncthreads();
  {
    int e = threadIdx.x >> 5, l = threadIdx.x & 31;
    float s = 0.f;
    for (int d0 = l; d0 < D_; d0 += 32) {
      float v = att_s[e * D_ + d0];
      s = fmaf(v, v, s);
    }
#pragma unroll
    for (int off = 16; off; off >>= 1) s += __shfl_xor(s, off);
    if (l == 0) rn[e] = 1.0f / sqrtf(s);
  }
  __syncthreads();
  int w = threadIdx.x >> 6, lane = threadIdx.x & 63;
  int e2 = lane & 7, ch = lane >> 3;
  float* rw = red[w];
  for (int i = 0; i < 8; ++i) {
    int t = b * N_ + tile * 32 + w * 8 + i;
    const float* xp = x + t * D_ + lane * 8;
    float4 xa = *(const float4*)xp;
    float4 xb4 = *(const float4*)(xp + 4);
    float p[8];
#pragma unroll
    for (int e = 0; e < 8; ++e) {
      const float* apt = att_s + e * D_ + lane * 8;
      float4 a0 = *(const float4*)apt;
      float4 a1 = *(const float4*)(apt + 4);
      float s = a0.x * xa.x;
      s = fmaf(a0.y, xa.y, s); s = fmaf(a0.z, xa.z, s); s = fmaf(a0.w, xa.w, s);
      s = fmaf(a1.x, xb4.x, s); s = fmaf(a1.y, xb4.y, s);
      s = fmaf(a1.z, xb4.z, s); s = fmaf(a1.w, xb4.w, s);
      p[e] = s;
    }
#pragma unroll
    for (int e = 0; e < 8; ++e) rw[e * 65 + lane] = p[e];
    float s = 0.f;
#pragma unroll
    for (int k = 0; k < 8; ++k) s += rw[e2 * 65 + ch * 8 + k];
    s += __shfl_xor(s, 8); s += __shfl_xor(s, 16); s += __shfl_xor(s, 32);
    float sc = s * rn[e2];
    int be = e2;
#pragma unroll
    for (int off = 1; off < 8; off <<= 1) {
      float o = __shfl_xor(sc, off);
      int oe = __shfl_xor(be, off);
      if (o > sc || (o == sc && oe < be)) { sc = o; be = oe; }
    }
    if (lane == 0) {
      int slot = atomicAdd(&bcnt[be], 1);
      blist[be][slot] = t;
    }
  }
  __syncthreads();
  int e = threadIdx.x >> 5, r = threadIdx.x & 31;
  int ce = bcnt[e];
  int gs = 0;
  if (r == 0 && ce > 0) gs = atomicAdd(&cnt[e * 32], ce);
  gs = __shfl(gs, (threadIdx.x & 63) & 32);
  for (int k2 = r; k2 < ce; k2 += 32) tok[e * BN + gs + k2] = blist[e][k2];
}

// zc[b][e][p] = att[b,e]·weff[e,1,:,p] + bc[e]*sum_l Wp[e,l,p] + bp[e,p]
__global__ __launch_bounds__(128) void k_zc(const float* __restrict__ att,
        const __hip_bfloat16* __restrict__ weff, const float* __restrict__ WpT,
        const float* __restrict__ bc, const float* __restrict__ bp,
        float* __restrict__ zc) {
  int b = blockIdx.x >> 3, e = blockIdx.x & 7;
  int p = threadIdx.x;
  if (p >= P_) return;
  const short* wrow = (const short*)(weff + ((e * 2 + 1) * P_ + p) * D_);
  const float* arow = att + (b * E_ + e) * D_;
  const float* wprow = WpT + (e * P_ + p) * D_;
  float acc = 0.f, s2 = 0.f;
  for (int m = 0; m < D_; m += 8) {
    short8 w8 = *(const short8*)(wrow + m);
    float4 a0 = *(const float4*)(arow + m);
    float4 a1 = *(const float4*)(arow + m + 4);
    float4 q0 = *(const float4*)(wprow + m);
    float4 q1 = *(const float4*)(wprow + m + 4);
    acc = fmaf(a0.x, b2f(w8[0]), acc); acc = fmaf(a0.y, b2f(w8[1]), acc);
    acc = fmaf(a0.z, b2f(w8[2]), acc); acc = fmaf(a0.w, b2f(w8[3]), acc);
    acc = fmaf(a1.x, b2f(w8[4]), acc); acc = fmaf(a1.y, b2f(w8[5]), acc);
    acc = fmaf(a1.z, b2f(w8[6]), acc); acc = fmaf(a1.w, b2f(w8[7]), acc);
    s2 += q0.x + q0.y + q0.z + q0.w + q1.x + q1.y + q1.z + q1.w;
  }
  zc[(b * E_ + e) * P_ + p] = acc + bc[e] * s2 + bp[e * P_ + p];
}

// grouped final GEMM v2: exactly-sized segmented grid, 256 threads (4 waves),
// 32 tokens x 96 cols per block. Wave (mw,nw): rows mw*16..+16, cols nw*48..+48.
__global__ __launch_bounds__(256) void k_final(const float* __restrict__ x,
        const __hip_bfloat16* __restrict__ weff, const float* __restrict__ zc,
        const int* __restrict__ cnt, const int* __restrict__ tok,
        float* __restrict__ out) {
  __shared__ __align__(16) unsigned short xsb[32 * 520];
  __shared__ int toks[32];
  int g = blockIdx.x;
  // per-expert block-count prefix (redundant per thread; 8 L2 loads)
  int cl_e[E_], bs[E_ + 1];
  bs[0] = 0;
#pragma unroll
  for (int e = 0; e < E_; ++e) {
    cl_e[e] = cnt[e * 32];
    bs[e + 1] = bs[e] + ((cl_e[e] + 31) >> 5);
  }
  if (g >= bs[E_]) return;
  int e = 0;
#pragma unroll
  for (int k = 1; k < E_; ++k) if (g >= bs[k]) e = k;
  int base = (g - bs[e]) * 32;
  int cnt_e = cl_e[e];
  int cl = cnt_e - base; if (cl > 32) cl = 32;
  int tid = threadIdx.x;
  if (tid < 32) toks[tid] = (tid < cl) ? tok[e * BN + base + tid] : tok[e * BN + base];
  __syncthreads();
  for (int idx = tid; idx < 32 * 128; idx += 256) {
    int r = idx >> 7, c4 = (idx & 127) * 4;
    float4 v = *(const float4*)(x + toks[r] * D_ + c4);
    ushort4 u4;
    u4.x = f2b(v.x); u4.y = f2b(v.y); u4.z = f2b(v.z); u4.w = f2b(v.w);
    *(ushort4*)(xsb + r * 520 + c4) = u4;
  }
  __syncthreads();
  int wave = tid >> 6, lane = tid & 63;
  int mw = wave & 1, nw = wave >> 1;
  int m16 = lane & 15, quad = lane >> 4;
  const short* w0 = (const short*)(weff + (e * 2 + 0) * P_ * D_);
  f32x4 acc[3];
#pragma unroll
  for (int nt = 0; nt < 3; ++nt) acc[nt] = (f32x4){0.f, 0.f, 0.f, 0.f};
  const short* arow = (const short*)xsb + (mw * 16 + m16) * 520 + quad * 8;
  const short* brow = w0 + (nw * 48 + m16) * D_ + quad * 8;
  for (int kt = 0; kt < 16; ++kt) {
    int koff = kt * 32;
    short8 a = *(const short8*)(arow + koff);
#pragma unroll
    for (int nt = 0; nt < 3; ++nt) {
      short8 bf = *(const short8*)(brow + nt * 16 * D_ + koff);
      acc[nt] = __builtin_amdgcn_mfma_f32_16x16x32_bf16(a, bf, acc[nt], 0, 0, 0);
    }
  }
#pragma unroll
  for (int nt = 0; nt < 3; ++nt)
#pragma unroll
    for (int rr = 0; rr < 4; ++rr) {
      int row = mw * 16 + quad * 4 + rr;
      if (row < cl) {
        int tg = toks[row];
        int bb = tg >> 9;
        int p = nw * 48 + nt * 16 + m16;
        out[tg * P_ + p] = acc[nt][rr] + zc[(bb * E_ + e) * P_ + p];
      }
    }
}

extern "C" void kernel_launch(void* const* d_in, const int* in_sizes, int n_in,
                              void* d_out, int out_size, void* d_ws, size_t ws_size,
                              hipStream_t stream) {
  const float* x      = (const float*)d_in[0];
  const float* router = (const float*)d_in[1];
  const float* Wq     = (const float*)d_in[2];
  const float* bq     = (const float*)d_in[3];
  const float* Wk     = (const float*)d_in[4];
  const float* bk     = (const float*)d_in[5];
  const float* Wv     = (const float*)d_in[6];
  const float* bv     = (const float*)d_in[7];
  const float* Wo     = (const float*)d_in[8];
  const float* bo     = (const float*)d_in[9];
  const float* Wc     = (const float*)d_in[10];
  const float* bc     = (const float*)d_in[11];
  const float* Wp     = (const float*)d_in[12];
  const float* bp     = (const float*)d_in[13];
  float* out = (float*)d_out;
  float* w = (float*)d_ws;

  float* q    = w + OQ;
  float* M    = w + OM;
  float* c    = w + OC;
  float* A0   = w + OA;
  float* A1   = w + OA + B_ * HE * N_;
  float* u    = w + OU;
  float* ap   = w + OAP;
  float* att  = w + OATT;
  float* WpT  = w + OWPT;
  float* zc   = w + OZC;
  int*   cnt  = (int*)(w + OCNT);
  int*   tok  = (int*)(w + OTOK);
  __hip_bfloat16* weff = (__hip_bfloat16*)(w + OWEFF);
  float* up   = w + OUP;

  hipMemsetAsync(w + OQ, 0, 4096 * sizeof(float), stream);
  hipMemsetAsync(cnt, 0, 256 * sizeof(int), stream);
  k_q<<<64, 256, 0, stream>>>(router, Wq, bq, q);
  k_m<<<64, 256, 0, stream>>>(Wk, bk, q, M, c);
  k_logits<<<1024, 256, 0, stream>>>(x, M, A0);
  k_softmax<<<1024, 256, 0, stream>>>(A0, A1, c);
  k_u2<<<dim3(8, 32), 512, 0, stream>>>(x, A0, up);
  k_ured<<<512, 256, 0, stream>>>(up, u);
  k_attpre<<<128, 256, 0, stream>>>(u, Wv, bv, ap);
  k_att<<<128, 256, 0, stream>>>(ap, Wo, bo, att);
  k_wpt<<<64, 256, 0, stream>>>(Wp, WpT);
  k_weff<<<3072, 256, 0, stream>>>(Wc, WpT, weff);
  k_route2<<<512, 256, 0, stream>>>(x, att, cnt, tok);
  k_zc<<<256, 128, 0, stream>>>(att, weff, WpT, bc, bp, zc);
  k_final<<<520, 256, 0, stream>>>(x, weff, zc, cnt, tok, out);
}

// Round 5
// 268.815 us; speedup vs baseline: 1.6371x; 1.0221x over previous
//
#include <hip/hip_runtime.h>
#include <hip/hip_bf16.h>

#define B_ 32
#define N_ 512
#define D_ 512
#define E_ 8
#define P_ 96
#define KC 25
#define H_ 4
#define DK 128
#define HE 32
#define BN 16384

typedef short short8 __attribute__((ext_vector_type(8)));
typedef float f32x4 __attribute__((ext_vector_type(4)));

// ws offsets (in floats)
#define OQ    0
#define OM    4096
#define OC    20480
#define OA    20736      /* 2 x 524288 partial logits -> softmaxed A in first half */
#define OU    1069312    /* 524288 */
#define OAP   1593600    /* 131072 */
#define OATT  1724672    /* 131072 */
#define OWPT  1855744    /* 393216 */
#define OZC   2248960    /* 24576 */
#define OCNT  2273536    /* 256 ints (8 counters strided by 32) */
#define OTOK  2273792    /* 131072 ints */
#define OWEFF 2404864    /* 786432 bf16 = 393216 float slots */
#define OUP   2798080    /* 4194304 floats: u partials [b][nq][32][512] */

__device__ __forceinline__ float b2f(short s) {
  unsigned u = ((unsigned)(unsigned short)s) << 16;
  return __builtin_bit_cast(float, u);
}
__device__ __forceinline__ unsigned short f2b(float f) {
  return __builtin_bit_cast(unsigned short, __float2bfloat16(f));
}

// q[e][i] = router[e]·Wq[:,i] + bq[i]  — partial-sum version, 64 blocks.
__global__ __launch_bounds__(256) void k_q(const float* __restrict__ router,
        const float* __restrict__ Wq, const float* __restrict__ bq,
        float* __restrict__ q) {
  __shared__ float rs[8][64];
  int iblk = blockIdx.x & 7, dblk = blockIdx.x >> 3;
  int i = iblk * 64 + (threadIdx.x & 63);
  int eg = threadIdx.x >> 6;  // 0..3 -> experts {2eg, 2eg+1}
  for (int idx = threadIdx.x; idx < 512; idx += 256) {
    int e = idx >> 6, d = idx & 63;
    rs[e][d] = router[e * D_ + dblk * 64 + d];
  }
  __syncthreads();
  float a0 = 0.f, a1 = 0.f;
  const float* wp = Wq + dblk * 64 * D_ + i;
#pragma unroll 8
  for (int d = 0; d < 64; ++d) {
    float w = wp[d * D_];
    a0 = fmaf(rs[eg * 2][d], w, a0);
    a1 = fmaf(rs[eg * 2 + 1][d], w, a1);
  }
  if (dblk == 0) { float b = bq[i]; a0 += b; a1 += b; }
  atomicAdd(&q[(eg * 2) * D_ + i], a0);
  atomicAdd(&q[(eg * 2 + 1) * D_ + i], a1);
}

// M[he][d0] = sum_j Wk[d0, h*128+j] * q[e, h*128+j];  c[he] = q[e,h-blk]·bk[h-blk]
__global__ __launch_bounds__(256) void k_m(const float* __restrict__ Wk,
        const float* __restrict__ bk, const float* __restrict__ q,
        float* __restrict__ M, float* __restrict__ c) {
  int he = blockIdx.x >> 1;
  int ch = blockIdx.x & 1;
  int d0 = ch * 256 + threadIdx.x;
  int h = he >> 3, e = he & 7;
  const float* qrow = q + e * D_ + h * DK;
  const float* wrow = Wk + d0 * D_ + h * DK;
  float acc = 0.f;
  for (int j = 0; j < DK; j += 4) {
    float4 wv = *(const float4*)(wrow + j);
    float4 qv = *(const float4*)(qrow + j);
    acc = fmaf(wv.x, qv.x, acc); acc = fmaf(wv.y, qv.y, acc);
    acc = fmaf(wv.z, qv.z, acc); acc = fmaf(wv.w, qv.w, acc);
  }
  M[he * D_ + d0] = acc;
  if (ch == 0 && threadIdx.x == 0) {
    float cc = 0.f;
    for (int j = 0; j < DK; ++j) cc = fmaf(qrow[j], bk[h * DK + j], cc);
    c[he] = cc;
  }
}

// logits v3: register-tiled LDS GEMM. Block = (b, 64-token tile, K-half).
// 128 threads: thread (nt=tid&15, ht=tid>>4) owns 4n x 4he, n = nt+16i, he = ht+8j.
// Apart[dh][b][he][n] = x[b,n,dh-half]·M[he,dh-half]
__global__ __launch_bounds__(128) void k_logits(const float* __restrict__ x,
        const float* __restrict__ M, float* __restrict__ Apart) {
  __shared__ float xs[64 * 132];
  __shared__ float Ms[32 * 132];
  int dh = blockIdx.x & 1;
  int nt8 = (blockIdx.x >> 1) & 7;
  int b = blockIdx.x >> 4;
  int tid = threadIdx.x;
  const float* xb = x + (b * N_ + nt8 * 64) * D_ + dh * 256;
  const float* Mb = M + dh * 256;
  float acc[4][4] = {{0.f}};
  for (int kc = 0; kc < 2; ++kc) {
    // stage x chunk: 64 rows x 128 cols
    for (int idx = tid; idx < 2048; idx += 128) {
      int r = idx >> 5, c4 = (idx & 31) * 4;
      *(float4*)(xs + r * 132 + c4) = *(const float4*)(xb + r * D_ + kc * 128 + c4);
    }
    // stage M chunk: 32 rows x 128 cols
    for (int idx = tid; idx < 1024; idx += 128) {
      int r = idx >> 5, c4 = (idx & 31) * 4;
      *(float4*)(Ms + r * 132 + c4) = *(const float4*)(Mb + r * D_ + kc * 128 + c4);
    }
    __syncthreads();
    int nt = tid & 15, ht = tid >> 4;
#pragma unroll 4
    for (int d4 = 0; d4 < 128; d4 += 4) {
      float4 xv[4], mv[4];
#pragma unroll
      for (int i = 0; i < 4; ++i)
        xv[i] = *(const float4*)(xs + (nt + 16 * i) * 132 + d4);
#pragma unroll
      for (int j = 0; j < 4; ++j)
        mv[j] = *(const float4*)(Ms + (ht + 8 * j) * 132 + d4);
#pragma unroll
      for (int i = 0; i < 4; ++i)
#pragma unroll
        for (int j = 0; j < 4; ++j) {
          float s = acc[i][j];
          s = fmaf(xv[i].x, mv[j].x, s);
          s = fmaf(xv[i].y, mv[j].y, s);
          s = fmaf(xv[i].z, mv[j].z, s);
          s = fmaf(xv[i].w, mv[j].w, s);
          acc[i][j] = s;
        }
    }
    __syncthreads();
  }
  int nt = tid & 15, ht = tid >> 4;
  float* Ad = Apart + dh * (B_ * HE * N_);
#pragma unroll
  for (int j = 0; j < 4; ++j) {
    int he = ht + 8 * j;
#pragma unroll
    for (int i = 0; i < 4; ++i)
      Ad[(b * HE + he) * N_ + nt8 * 64 + nt + 16 * i] = acc[i][j];
  }
}

// softmax over n per (b,he) row; combines d-half partials, applies scale and c[he]
__global__ __launch_bounds__(256) void k_softmax(float* __restrict__ A0,
        const float* __restrict__ A1, const float* __restrict__ c) {
  int row = blockIdx.x;
  float* p0 = A0 + row * N_;
  const float* p1 = A1 + row * N_;
  float cc = c[row & 31];
  int t = threadIdx.x;
  const float scale = 0.08838834764831845f;
  float v0 = scale * (p0[t] + p1[t] + cc);
  float v1 = scale * (p0[t + 256] + p1[t + 256] + cc);
  __shared__ float red[4], red2[4];
  float m = fmaxf(v0, v1);
#pragma unroll
  for (int off = 32; off; off >>= 1) m = fmaxf(m, __shfl_xor(m, off));
  if ((t & 63) == 0) red[t >> 6] = m;
  __syncthreads();
  m = fmaxf(fmaxf(red[0], red[1]), fmaxf(red[2], red[3]));
  float e0 = expf(v0 - m), e1 = expf(v1 - m);
  float s = e0 + e1;
#pragma unroll
  for (int off = 32; off; off >>= 1) s += __shfl_xor(s, off);
  if ((t & 63) == 0) red2[t >> 6] = s;
  __syncthreads();
  s = red2[0] + red2[1] + red2[2] + red2[3];
  float inv = 1.0f / s;
  p0[t] = e0 * inv;
  p0[t + 256] = e1 * inv;
}

// u partials over n-slices: up[b][nq][he][d] = sum_{n in slice} A[b,he,n]*x[b,n,d]
__global__ __launch_bounds__(512) void k_u2(const float* __restrict__ x,
        const float* __restrict__ A, float* __restrict__ up) {
  __shared__ float As[64 * 33];
  int nq = blockIdx.x, b = blockIdx.y;
  for (int idx = threadIdx.x; idx < 64 * 32; idx += 512) {
    int n = idx & 63, he = idx >> 6;
    As[n * 33 + he] = A[(b * HE + he) * N_ + nq * 64 + n];
  }
  __syncthreads();
  int dq = threadIdx.x & 127, hg = threadIdx.x >> 7;  // hg uniform per wave
  const float* xb = x + (b * N_ + nq * 64) * D_ + dq * 4;
  float acc[8][4];
#pragma unroll
  for (int j = 0; j < 8; ++j)
#pragma unroll
    for (int k = 0; k < 4; ++k) acc[j][k] = 0.f;
  for (int n = 0; n < 64; ++n) {
    float4 xv = *(const float4*)(xb + n * D_);
    const float* ar = As + n * 33 + hg * 8;
#pragma unroll
    for (int j = 0; j < 8; ++j) {
      float a = ar[j];
      acc[j][0] = fmaf(a, xv.x, acc[j][0]);
      acc[j][1] = fmaf(a, xv.y, acc[j][1]);
      acc[j][2] = fmaf(a, xv.z, acc[j][2]);
      acc[j][3] = fmaf(a, xv.w, acc[j][3]);
    }
  }
  float* o = up + (((b * 8 + nq) * HE) + hg * 8) * D_ + dq * 4;
#pragma unroll
  for (int j = 0; j < 8; ++j) {
    float4 v; v.x = acc[j][0]; v.y = acc[j][1]; v.z = acc[j][2]; v.w = acc[j][3];
    *(float4*)(o + j * D_) = v;
  }
}

// u[b][he][d] = sum_nq up[b][nq][he][d]
__global__ __launch_bounds__(256) void k_ured(const float* __restrict__ up,
        float* __restrict__ u) {
  int o4 = (blockIdx.x * 256 + threadIdx.x) * 4;
  int bhe = o4 >> 9, d = o4 & 511;
  int b = bhe >> 5, he = bhe & 31;
  float4 s = {0.f, 0.f, 0.f, 0.f};
#pragma unroll
  for (int nq = 0; nq < 8; ++nq) {
    float4 v = *(const float4*)(up + (((b * 8 + nq) * HE + he) << 9) + d);
    s.x += v.x; s.y += v.y; s.z += v.z; s.w += v.w;
  }
  *(float4*)(u + o4) = s;
}

// att_pre[b][e][i] = sum_d u[b, h(i)*8+e, d] * Wv[d,i] + bv[i]   (h(i)=i>>7)
__global__ __launch_bounds__(256) void k_attpre(const float* __restrict__ u,
        const float* __restrict__ Wv, const float* __restrict__ bv,
        float* __restrict__ ap) {
  __shared__ float us[8 * D_];
  int e = blockIdx.x & 7;
  int ic = (blockIdx.x >> 3) & 3;
  int bq = blockIdx.x >> 5;
  for (int idx = threadIdx.x; idx < 8 * D_; idx += 256) {
    int rr = idx >> 9, d = idx & 511;
    us[idx] = u[((bq * 8 + rr) * HE + ic * 8 + e) * D_ + d];
  }
  __syncthreads();
  int i = ic * 128 + (threadIdx.x & 127);
  int bg = threadIdx.x >> 7;
  const float* usb = us + bg * 4 * D_;
  float acc[4] = {0.f, 0.f, 0.f, 0.f};
  for (int d = 0; d < D_; d += 4) {
    float w0 = Wv[(d + 0) * D_ + i];
    float w1 = Wv[(d + 1) * D_ + i];
    float w2 = Wv[(d + 2) * D_ + i];
    float w3 = Wv[(d + 3) * D_ + i];
#pragma unroll
    for (int r = 0; r < 4; ++r) {
      float4 uv = *(const float4*)(usb + r * D_ + d);
      float s = acc[r];
      s = fmaf(uv.x, w0, s); s = fmaf(uv.y, w1, s);
      s = fmaf(uv.z, w2, s); s = fmaf(uv.w, w3, s);
      acc[r] = s;
    }
  }
  float bvi = bv[i];
#pragma unroll
  for (int r = 0; r < 4; ++r)
    ap[((bq * 8 + bg * 4 + r) * E_ + e) * D_ + i] = acc[r] + bvi;
}

// att[b][e][o] = sum_i ap[b,e,i] * Wo[i,o] + bo[o]
__global__ __launch_bounds__(256) void k_att(const float* __restrict__ ap,
        const float* __restrict__ Wo, const float* __restrict__ bo,
        float* __restrict__ att) {
  __shared__ float ps[8 * D_];
  int b = blockIdx.x >> 2, oc = blockIdx.x & 3;
  for (int idx = threadIdx.x; idx < 8 * D_; idx += 256)
    ps[idx] = ap[b * E_ * D_ + idx];
  __syncthreads();
  int o = oc * 128 + (threadIdx.x & 127);
  int eg = threadIdx.x >> 7;
  const float* pe = ps + eg * 4 * D_;
  float acc[4] = {0.f, 0.f, 0.f, 0.f};
  for (int i2 = 0; i2 < D_; i2 += 4) {
    float w0 = Wo[(i2 + 0) * D_ + o];
    float w1 = Wo[(i2 + 1) * D_ + o];
    float w2 = Wo[(i2 + 2) * D_ + o];
    float w3 = Wo[(i2 + 3) * D_ + o];
#pragma unroll
    for (int r = 0; r < 4; ++r) {
      float4 pv = *(const float4*)(pe + r * D_ + i2);
      float s = acc[r];
      s = fmaf(pv.x, w0, s); s = fmaf(pv.y, w1, s);
      s = fmaf(pv.z, w2, s); s = fmaf(pv.w, w3, s);
      acc[r] = s;
    }
  }
  float boo = bo[o];
#pragma unroll
  for (int r = 0; r < 4; ++r)
    att[(b * E_ + eg * 4 + r) * D_ + o] = acc[r] + boo;
}

// WpT[e][p][l] = Wp[e][l][p]
__global__ __launch_bounds__(256) void k_wpt(const float* __restrict__ Wp,
        float* __restrict__ WpT) {
  __shared__ float tile[64 * 97];
  int e = blockIdx.x >> 3, lt = blockIdx.x & 7;
  for (int idx = threadIdx.x; idx < 64 * 96; idx += 256) {
    int l = idx / 96, p = idx - l * 96;
    tile[l * 97 + p] = Wp[(e * D_ + lt * 64 + l) * P_ + p];
  }
  __syncthreads();
  for (int idx = threadIdx.x; idx < 96 * 64; idx += 256) {
    int p = idx >> 6, l = idx & 63;
    WpT[(e * P_ + p) * D_ + lt * 64 + l] = tile[l * 97 + p];
  }
}

// weff (bf16) [e][j][p][m] = sum_k Wc[e,j,k] * Wp[e, m-k+12, p]
__global__ __launch_bounds__(256) void k_weff(const float* __restrict__ Wc,
        const float* __restrict__ WpT, __hip_bfloat16* __restrict__ weff) {
  int flat = blockIdx.x * 256 + threadIdx.x;
  int m = flat & 511;
  int rest = flat >> 9;       // (e*2+j)*96 + p
  int p = rest % 96;
  int ej = rest / 96;
  int e = ej >> 1, j = ej & 1;
  const float* wprow = WpT + (e * P_ + p) * D_;
  const float* wc = Wc + (e * 2 + j) * KC;
  float acc = 0.f;
#pragma unroll
  for (int k = 0; k < KC; ++k) {
    int l = m - k + 12;
    if (l >= 0 && l < D_) acc = fmaf(wc[k], wprow[l], acc);
  }
  weff[flat] = __float2bfloat16(acc);
}

// routing v2: one wave per token. score[e] = att[b,e]·x[b,n] / ||att[b,e]||,
// argmax -> per-block expert lists -> one global atomic per (block,expert).
__global__ __launch_bounds__(256) void k_route2(const float* __restrict__ x,
        const float* __restrict__ att, int* __restrict__ cnt,
        int* __restrict__ tok) {
  __shared__ float att_s[8 * D_];
  __shared__ float rn[8];
  __shared__ float red[4][520];
  __shared__ int blist[8][32];
  __shared__ int bcnt[8];
  int b = blockIdx.x >> 4, tile = blockIdx.x & 15;
  for (int idx = threadIdx.x; idx < 1024; idx += 256)
    *(float4*)(att_s + idx * 4) = *(const float4*)(att + b * E_ * D_ + idx * 4);
  if (threadIdx.x < 8) bcnt[threadIdx.x] = 0;
  __syncthreads();
  {
    int e = threadIdx.x >> 5, l = threadIdx.x & 31;
    float s = 0.f;
    for (int d0 = l; d0 < D_; d0 += 32) {
      float v = att_s[e * D_ + d0];
      s = fmaf(v, v, s);
    }
#pragma unroll
    for (int off = 16; off; off >>= 1) s += __shfl_xor(s, off);
    if (l == 0) rn[e] = 1.0f / sqrtf(s);
  }
  __syncthreads();
  int w = threadIdx.x >> 6, lane = threadIdx.x & 63;
  int e2 = lane & 7, ch = lane >> 3;
  float* rw = red[w];
  for (int i = 0; i < 8; ++i) {
    int t = b * N_ + tile * 32 + w * 8 + i;
    const float* xp = x + t * D_ + lane * 8;
    float4 xa = *(const float4*)xp;
    float4 xb4 = *(const float4*)(xp + 4);
    float p[8];
#pragma unroll
    for (int e = 0; e < 8; ++e) {
      const float* apt = att_s + e * D_ + lane * 8;
      float4 a0 = *(const float4*)apt;
      float4 a1 = *(const float4*)(apt + 4);
      float s = a0.x * xa.x;
      s = fmaf(a0.y, xa.y, s); s = fmaf(a0.z, xa.z, s); s = fmaf(a0.w, xa.w, s);
      s = fmaf(a1.x, xb4.x, s); s = fmaf(a1.y, xb4.y, s);
      s = fmaf(a1.z, xb4.z, s); s = fmaf(a1.w, xb4.w, s);
      p[e] = s;
    }
#pragma unroll
    for (int e = 0; e < 8; ++e) rw[e * 65 + lane] = p[e];
    float s = 0.f;
#pragma unroll
    for (int k = 0; k < 8; ++k) s += rw[e2 * 65 + ch * 8 + k];
    s += __shfl_xor(s, 8); s += __shfl_xor(s, 16); s += __shfl_xor(s, 32);
    float sc = s * rn[e2];
    int be = e2;
#pragma unroll
    for (int off = 1; off < 8; off <<= 1) {
      float o = __shfl_xor(sc, off);
      int oe = __shfl_xor(be, off);
      if (o > sc || (o == sc && oe < be)) { sc = o; be = oe; }
    }
    if (lane == 0) {
      int slot = atomicAdd(&bcnt[be], 1);
      blist[be][slot] = t;
    }
  }
  __syncthreads();
  int e = threadIdx.x >> 5, r = threadIdx.x & 31;
  int ce = bcnt[e];
  int gs = 0;
  if (r == 0 && ce > 0) gs = atomicAdd(&cnt[e * 32], ce);
  gs = __shfl(gs, (threadIdx.x & 63) & 32);
  for (int k2 = r; k2 < ce; k2 += 32) tok[e * BN + gs + k2] = blist[e][k2];
}

// zc[b][e][p] = att[b,e]·weff[e,1,:,p] + bc[e]*sum_l Wp[e,l,p] + bp[e,p]
__global__ __launch_bounds__(128) void k_zc(const float* __restrict__ att,
        const __hip_bfloat16* __restrict__ weff, const float* __restrict__ WpT,
        const float* __restrict__ bc, const float* __restrict__ bp,
        float* __restrict__ zc) {
  int b = blockIdx.x >> 3, e = blockIdx.x & 7;
  int p = threadIdx.x;
  if (p >= P_) return;
  const short* wrow = (const short*)(weff + ((e * 2 + 1) * P_ + p) * D_);
  const float* arow = att + (b * E_ + e) * D_;
  const float* wprow = WpT + (e * P_ + p) * D_;
  float acc = 0.f, s2 = 0.f;
  for (int m = 0; m < D_; m += 8) {
    short8 w8 = *(const short8*)(wrow + m);
    float4 a0 = *(const float4*)(arow + m);
    float4 a1 = *(const float4*)(arow + m + 4);
    float4 q0 = *(const float4*)(wprow + m);
    float4 q1 = *(const float4*)(wprow + m + 4);
    acc = fmaf(a0.x, b2f(w8[0]), acc); acc = fmaf(a0.y, b2f(w8[1]), acc);
    acc = fmaf(a0.z, b2f(w8[2]), acc); acc = fmaf(a0.w, b2f(w8[3]), acc);
    acc = fmaf(a1.x, b2f(w8[4]), acc); acc = fmaf(a1.y, b2f(w8[5]), acc);
    acc = fmaf(a1.z, b2f(w8[6]), acc); acc = fmaf(a1.w, b2f(w8[7]), acc);
    s2 += q0.x + q0.y + q0.z + q0.w + q1.x + q1.y + q1.z + q1.w;
  }
  zc[(b * E_ + e) * P_ + p] = acc + bc[e] * s2 + bp[e * P_ + p];
}

// grouped final GEMM v2: exactly-sized segmented grid, 256 threads (4 waves),
// 32 tokens x 96 cols per block. Wave (mw,nw): rows mw*16..+16, cols nw*48..+48.
__global__ __launch_bounds__(256) void k_final(const float* __restrict__ x,
        const __hip_bfloat16* __restrict__ weff, const float* __restrict__ zc,
        const int* __restrict__ cnt, const int* __restrict__ tok,
        float* __restrict__ out) {
  __shared__ __align__(16) unsigned short xsb[32 * 520];
  __shared__ int toks[32];
  int g = blockIdx.x;
  // per-expert block-count prefix (redundant per thread; 8 L2 loads)
  int cl_e[E_], bs[E_ + 1];
  bs[0] = 0;
#pragma unroll
  for (int e = 0; e < E_; ++e) {
    cl_e[e] = cnt[e * 32];
    bs[e + 1] = bs[e] + ((cl_e[e] + 31) >> 5);
  }
  if (g >= bs[E_]) return;
  int e = 0;
#pragma unroll
  for (int k = 1; k < E_; ++k) if (g >= bs[k]) e = k;
  int base = (g - bs[e]) * 32;
  int cnt_e = cl_e[e];
  int cl = cnt_e - base; if (cl > 32) cl = 32;
  int tid = threadIdx.x;
  if (tid < 32) toks[tid] = (tid < cl) ? tok[e * BN + base + tid] : tok[e * BN + base];
  __syncthreads();
  for (int idx = tid; idx < 32 * 128; idx += 256) {
    int r = idx >> 7, c4 = (idx & 127) * 4;
    float4 v = *(const float4*)(x + toks[r] * D_ + c4);
    ushort4 u4;
    u4.x = f2b(v.x); u4.y = f2b(v.y); u4.z = f2b(v.z); u4.w = f2b(v.w);
    *(ushort4*)(xsb + r * 520 + c4) = u4;
  }
  __syncthreads();
  int wave = tid >> 6, lane = tid & 63;
  int mw = wave & 1, nw = wave >> 1;
  int m16 = lane & 15, quad = lane >> 4;
  const short* w0 = (const short*)(weff + (e * 2 + 0) * P_ * D_);
  f32x4 acc[3];
#pragma unroll
  for (int nt = 0; nt < 3; ++nt) acc[nt] = (f32x4){0.f, 0.f, 0.f, 0.f};
  const short* arow = (const short*)xsb + (mw * 16 + m16) * 520 + quad * 8;
  const short* brow = w0 + (nw * 48 + m16) * D_ + quad * 8;
  for (int kt = 0; kt < 16; ++kt) {
    int koff = kt * 32;
    short8 a = *(const short8*)(arow + koff);
#pragma unroll
    for (int nt = 0; nt < 3; ++nt) {
      short8 bf = *(const short8*)(brow + nt * 16 * D_ + koff);
      acc[nt] = __builtin_amdgcn_mfma_f32_16x16x32_bf16(a, bf, acc[nt], 0, 0, 0);
    }
  }
#pragma unroll
  for (int nt = 0; nt < 3; ++nt)
#pragma unroll
    for (int rr = 0; rr < 4; ++rr) {
      int row = mw * 16 + quad * 4 + rr;
      if (row < cl) {
        int tg = toks[row];
        int bb = tg >> 9;
        int p = nw * 48 + nt * 16 + m16;
        out[tg * P_ + p] = acc[nt][rr] + zc[(bb * E_ + e) * P_ + p];
      }
    }
}

extern "C" void kernel_launch(void* const* d_in, const int* in_sizes, int n_in,
                              void* d_out, int out_size, void* d_ws, size_t ws_size,
                              hipStream_t stream) {
  const float* x      = (const float*)d_in[0];
  const float* router = (const float*)d_in[1];
  const float* Wq     = (const float*)d_in[2];
  const float* bq     = (const float*)d_in[3];
  const float* Wk     = (const float*)d_in[4];
  const float* bk     = (const float*)d_in[5];
  const float* Wv     = (const float*)d_in[6];
  const float* bv     = (const float*)d_in[7];
  const float* Wo     = (const float*)d_in[8];
  const float* bo     = (const float*)d_in[9];
  const float* Wc     = (const float*)d_in[10];
  const float* bc     = (const float*)d_in[11];
  const float* Wp     = (const float*)d_in[12];
  const float* bp     = (const float*)d_in[13];
  float* out = (float*)d_out;
  float* w = (float*)d_ws;

  float* q    = w + OQ;
  float* M    = w + OM;
  float* c    = w + OC;
  float* A0   = w + OA;
  float* A1   = w + OA + B_ * HE * N_;
  float* u    = w + OU;
  float* ap   = w + OAP;
  float* att  = w + OATT;
  float* WpT  = w + OWPT;
  float* zc   = w + OZC;
  int*   cnt  = (int*)(w + OCNT);
  int*   tok  = (int*)(w + OTOK);
  __hip_bfloat16* weff = (__hip_bfloat16*)(w + OWEFF);
  float* up   = w + OUP;

  hipMemsetAsync(w + OQ, 0, 4096 * sizeof(float), stream);
  hipMemsetAsync(cnt, 0, 256 * sizeof(int), stream);
  k_q<<<64, 256, 0, stream>>>(router, Wq, bq, q);
  k_m<<<64, 256, 0, stream>>>(Wk, bk, q, M, c);
  k_logits<<<512, 128, 0, stream>>>(x, M, A0);
  k_softmax<<<1024, 256, 0, stream>>>(A0, A1, c);
  k_u2<<<dim3(8, 32), 512, 0, stream>>>(x, A0, up);
  k_ured<<<512, 256, 0, stream>>>(up, u);
  k_attpre<<<128, 256, 0, stream>>>(u, Wv, bv, ap);
  k_att<<<128, 256, 0, stream>>>(ap, Wo, bo, att);
  k_wpt<<<64, 256, 0, stream>>>(Wp, WpT);
  k_weff<<<3072, 256, 0, stream>>>(Wc, WpT, weff);
  k_route2<<<512, 256, 0, stream>>>(x, att, cnt, tok);
  k_zc<<<256, 128, 0, stream>>>(att, weff, WpT, bc, bp, zc);
  k_final<<<520, 256, 0, stream>>>(x, weff, zc, cnt, tok, out);
}